// Round 1
// baseline (445.972 us; speedup 1.0000x reference)
//
#include <hip/hip_runtime.h>
#include <hip/hip_bf16.h>

#define TPB 256
#define NEG_SLOPE 0.2f

// ---------- helpers ----------
__device__ __forceinline__ int getIdx(const void* p, int is32, long long i) {
  return is32 ? ((const int*)p)[i] : (int)((const long long*)p)[i];
}

// Detect whether edge_index storage is int32 (flag=1) or int64 (flag=0).
// Values are node ids < 2^31; if stored int32, reading u64 combines two ids
// and (almost surely) exceeds 2^32 within the first 64 words.
__global__ void k_detect(const void* __restrict__ ei, long long nSafe64, int* flag) {
  const unsigned long long* p = (const unsigned long long*)ei;
  int is32 = 0;
  for (long long i = 0; i < 64 && i < nSafe64; ++i)
    if (p[i] > 0xFFFFFFFFULL) is32 = 1;
  *flag = is32;
}

// ---------- layer 1: h1 = x @ W1  (N x 64) @ (64 x 64), fused alpha dots ----------
__global__ __launch_bounds__(TPB) void k_gemm1(
    const float* __restrict__ x, const float* __restrict__ W1,
    const float* __restrict__ aS, const float* __restrict__ aD,
    float* __restrict__ h1, float* __restrict__ asrc, float* __restrict__ adst, int N) {
  __shared__ float Wl[64 * 64];
  __shared__ float xr[4][64];
  int t = threadIdx.x;
  for (int i = t; i < 64 * 64; i += TPB) Wl[i] = W1[i];
  int w = t >> 6, lane = t & 63;
  int node = blockIdx.x * 4 + w;
  if (node < N) xr[w][lane] = x[(size_t)node * 64 + lane];
  __syncthreads();
  if (node >= N) return;
  float acc = 0.f;
#pragma unroll
  for (int k = 0; k < 64; ++k) acc = fmaf(xr[w][k], Wl[k * 64 + lane], acc);
  h1[(size_t)node * 64 + lane] = acc;
  // a_src1/a_dst1 are [2,32] flattened == index `lane` exactly (head = lane>>5)
  float vs = acc * aS[lane];
  float vd = acc * aD[lane];
#pragma unroll
  for (int m = 16; m >= 1; m >>= 1) {
    vs += __shfl_xor(vs, m, 64);
    vd += __shfl_xor(vd, m, 64);
  }
  if ((lane & 31) == 0) {
    asrc[node * 2 + (lane >> 5)] = vs;
    adst[node * 2 + (lane >> 5)] = vd;
  }
}

// ---------- layer 1 edge pass: wave per edge, 64 features, 2 heads ----------
__global__ __launch_bounds__(TPB) void k_edge_agg1(
    const void* __restrict__ ei, const int* __restrict__ dflag, int E, int Etot,
    const float* __restrict__ asrc, const float* __restrict__ adst,
    const float* __restrict__ h1, float* __restrict__ agg, float* __restrict__ denom) {
  int wid = (int)((blockIdx.x * (unsigned)TPB + threadIdx.x) >> 6);
  int lane = threadIdx.x & 63;
  if (wid >= Etot) return;
  int f = *dflag;
  int s, d;
  if (wid < E) {
    s = getIdx(ei, f, wid);
    d = getIdx(ei, f, (long long)E + wid);
  } else {
    s = d = wid - E;
  }
  int h = lane >> 5;
  float v = asrc[s * 2 + h] + adst[d * 2 + h];
  v = v > 0.f ? v : NEG_SLOPE * v;
  float ex = __expf(v);  // max-shift elided: |v| <~ 5, exp is exact enough in fp32
  if ((lane & 31) == 0) atomicAdd(&denom[d * 2 + h], ex);
  atomicAdd(&agg[(size_t)d * 64 + lane], ex * h1[(size_t)s * 64 + lane]);
}

// ---------- layer 1 normalize + bias + relu (in place) ----------
__global__ __launch_bounds__(TPB) void k_norm1(
    float* __restrict__ agg, const float* __restrict__ denom,
    const float* __restrict__ b, int N) {
  int i = blockIdx.x * TPB + threadIdx.x;
  if (i >= N * 64) return;
  int n = i >> 6, c = i & 63;
  float v = agg[i] / (denom[n * 2 + (c >> 5)] + 1e-16f) + b[c];
  agg[i] = v > 0.f ? v : 0.f;
}

// ---------- layer 2: h2 = out1 @ W2  (N x 64) @ (64 x 32), fused alpha dots ----------
__global__ __launch_bounds__(TPB) void k_gemm2(
    const float* __restrict__ in, const float* __restrict__ W2,
    const float* __restrict__ aS, const float* __restrict__ aD,
    float* __restrict__ h2, float* __restrict__ asrc, float* __restrict__ adst, int N) {
  __shared__ float Wl[64 * 32];
  __shared__ float xr[8][64];
  int t = threadIdx.x;
  for (int i = t; i < 64 * 32; i += TPB) Wl[i] = W2[i];
  int g = t >> 5, c = t & 31;
  int node = blockIdx.x * 8 + g;
  size_t base = (size_t)blockIdx.x * 8 * 64;
  for (int i = t; i < 512; i += TPB) {
    int nn = blockIdx.x * 8 + (i >> 6);
    if (nn < N) xr[i >> 6][i & 63] = in[base + i];
  }
  __syncthreads();
  if (node >= N) return;
  float acc = 0.f;
#pragma unroll
  for (int k = 0; k < 64; ++k) acc = fmaf(xr[g][k], Wl[k * 32 + c], acc);
  h2[(size_t)node * 32 + c] = acc;
  float vs = acc * aS[c];
  float vd = acc * aD[c];
#pragma unroll
  for (int m = 16; m >= 1; m >>= 1) {
    vs += __shfl_xor(vs, m, 64);
    vd += __shfl_xor(vd, m, 64);
  }
  if (c == 0) {
    asrc[node] = vs;
    adst[node] = vd;
  }
}

// ---------- layer 2 edge pass: half-wave per edge, 32 features, 1 head ----------
__global__ __launch_bounds__(TPB) void k_edge_agg2(
    const void* __restrict__ ei, const int* __restrict__ dflag, int E, int Etot,
    const float* __restrict__ asrc, const float* __restrict__ adst,
    const float* __restrict__ h2, float* __restrict__ agg, float* __restrict__ denom) {
  unsigned tid = blockIdx.x * (unsigned)TPB + threadIdx.x;
  int e = (int)(tid >> 5);
  int c = threadIdx.x & 31;
  if (e >= Etot) return;
  int f = *dflag;
  int s, d;
  if (e < E) {
    s = getIdx(ei, f, e);
    d = getIdx(ei, f, (long long)E + e);
  } else {
    s = d = e - E;
  }
  float v = asrc[s] + adst[d];
  v = v > 0.f ? v : NEG_SLOPE * v;
  float ex = __expf(v);
  if (c == 0) atomicAdd(&denom[d], ex);
  atomicAdd(&agg[(size_t)d * 32 + c], ex * h2[(size_t)s * 32 + c]);
}

// ---------- layer 2 normalize + bias -> d_out ----------
__global__ __launch_bounds__(TPB) void k_norm2(
    const float* __restrict__ agg, const float* __restrict__ denom,
    const float* __restrict__ b, float* __restrict__ out, int N) {
  int i = blockIdx.x * TPB + threadIdx.x;
  if (i >= N * 32) return;
  int n = i >> 5, c = i & 31;
  out[i] = agg[i] / (denom[n] + 1e-16f) + b[c];
}

extern "C" void kernel_launch(void* const* d_in, const int* in_sizes, int n_in,
                              void* d_out, int out_size, void* d_ws, size_t ws_size,
                              hipStream_t stream) {
  const float* x   = (const float*)d_in[0];
  const void*  ei  = d_in[1];
  const float* W1  = (const float*)d_in[2];
  const float* aS1 = (const float*)d_in[3];
  const float* aD1 = (const float*)d_in[4];
  const float* b1  = (const float*)d_in[5];
  const float* W2  = (const float*)d_in[6];
  const float* aS2 = (const float*)d_in[7];
  const float* aD2 = (const float*)d_in[8];
  const float* b2  = (const float*)d_in[9];
  float* out = (float*)d_out;

  int N = in_sizes[0] / 64;
  int E = in_sizes[1] / 2;
  int Etot = E + N;

  float* W = (float*)d_ws;
  size_t o = 0;
  float* agg1 = W + o; o += (size_t)N * 64;
  float* den1 = W + o; o += (size_t)N * 2;
  float* agg2 = W + o; o += (size_t)N * 32;
  float* den2 = W + o; o += (size_t)N;
  size_t zeroFloats = o;                 // contiguous zero-init block
  float* h1  = W + o; o += (size_t)N * 64;
  float* as1 = W + o; o += (size_t)N * 2;
  float* ad1 = W + o; o += (size_t)N * 2;
  float* h2  = W + o; o += (size_t)N * 32;
  float* as2 = W + o; o += (size_t)N;
  float* ad2 = W + o; o += (size_t)N;
  int* flag  = (int*)(W + o);

  hipMemsetAsync(d_ws, 0, zeroFloats * sizeof(float), stream);
  k_detect<<<1, 1, 0, stream>>>(ei, (long long)E, flag);

  k_gemm1<<<(N + 3) / 4, TPB, 0, stream>>>(x, W1, aS1, aD1, h1, as1, ad1, N);
  k_edge_agg1<<<(Etot + 3) / 4, TPB, 0, stream>>>(ei, flag, E, Etot, as1, ad1, h1, agg1, den1);
  k_norm1<<<(N * 64 + TPB - 1) / TPB, TPB, 0, stream>>>(agg1, den1, b1, N);

  k_gemm2<<<(N + 7) / 8, TPB, 0, stream>>>(agg1, W2, aS2, aD2, h2, as2, ad2, N);
  k_edge_agg2<<<(Etot + 7) / 8, TPB, 0, stream>>>(ei, flag, E, Etot, as2, ad2, h2, agg2, den2);
  k_norm2<<<(N * 32 + TPB - 1) / TPB, TPB, 0, stream>>>(agg2, den2, b2, out, N);
}

// Round 2
// 245.425 us; speedup vs baseline: 1.8171x; 1.8171x over previous
//
#include <hip/hip_runtime.h>
#include <hip/hip_bf16.h>

#define TPB 256
#define NEG_SLOPE 0.2f

// ---------- helpers ----------
__device__ __forceinline__ int getIdx(const void* p, int is32, long long i) {
  return is32 ? ((const int*)p)[i] : (int)((const long long*)p)[i];
}

// Detect whether edge_index storage is int32 (flag=1) or int64 (flag=0).
__global__ void k_detect(const void* __restrict__ ei, long long nSafe64, int* flag) {
  const unsigned long long* p = (const unsigned long long*)ei;
  int is32 = 0;
  for (long long i = 0; i < 64 && i < nSafe64; ++i)
    if (p[i] > 0xFFFFFFFFULL) is32 = 1;
  *flag = is32;
}

// ---------- CSR build ----------
__global__ __launch_bounds__(TPB) void k_count(
    const void* __restrict__ ei, const int* __restrict__ dflag, int E, int Etot,
    int* __restrict__ counts) {
  int e = blockIdx.x * TPB + threadIdx.x;
  if (e >= Etot) return;
  int d = (e < E) ? getIdx(ei, *dflag, (long long)E + e) : e - E;
  atomicAdd(&counts[d], 1);
}

// per-block exclusive scan; block sums out
__global__ __launch_bounds__(TPB) void k_scan1(
    const int* __restrict__ counts, int* __restrict__ excl, int* __restrict__ bsum, int N) {
  __shared__ int tmp[TPB];
  int i = blockIdx.x * TPB + threadIdx.x;
  int v = (i < N) ? counts[i] : 0;
  tmp[threadIdx.x] = v;
  __syncthreads();
  for (int off = 1; off < TPB; off <<= 1) {
    int t = (threadIdx.x >= off) ? tmp[threadIdx.x - off] : 0;
    __syncthreads();
    tmp[threadIdx.x] += t;
    __syncthreads();
  }
  if (i < N) excl[i] = tmp[threadIdx.x] - v;
  if (threadIdx.x == TPB - 1) bsum[blockIdx.x] = tmp[threadIdx.x];
}

// single-block exclusive scan of block sums (loop-carried)
__global__ __launch_bounds__(TPB) void k_scan2(int* __restrict__ bsum, int nb) {
  __shared__ int tmp[TPB];
  __shared__ int carrySh;
  if (threadIdx.x == 0) carrySh = 0;
  __syncthreads();
  for (int base = 0; base < nb; base += TPB) {
    int i = base + threadIdx.x;
    int v = (i < nb) ? bsum[i] : 0;
    tmp[threadIdx.x] = v;
    __syncthreads();
    for (int off = 1; off < TPB; off <<= 1) {
      int t = (threadIdx.x >= off) ? tmp[threadIdx.x - off] : 0;
      __syncthreads();
      tmp[threadIdx.x] += t;
      __syncthreads();
    }
    int carry = carrySh;
    if (i < nb) bsum[i] = carry + tmp[threadIdx.x] - v;
    __syncthreads();
    if (threadIdx.x == 0) carrySh = carry + tmp[TPB - 1];
    __syncthreads();
  }
}

__global__ __launch_bounds__(TPB) void k_addoff(
    const int* __restrict__ excl, const int* __restrict__ bsum,
    int* __restrict__ rowptr, int* __restrict__ cursor, int N, int Etot) {
  int i = blockIdx.x * TPB + threadIdx.x;
  if (i < N) {
    int v = excl[i] + bsum[blockIdx.x];
    rowptr[i] = v;
    cursor[i] = v;
  }
  if (i == 0) rowptr[N] = Etot;
}

__global__ __launch_bounds__(TPB) void k_scatter(
    const void* __restrict__ ei, const int* __restrict__ dflag, int E, int Etot,
    int* __restrict__ cursor, int* __restrict__ csr_src) {
  int e = blockIdx.x * TPB + threadIdx.x;
  if (e >= Etot) return;
  int s, d;
  if (e < E) {
    int f = *dflag;
    s = getIdx(ei, f, e);
    d = getIdx(ei, f, (long long)E + e);
  } else {
    s = d = e - E;
  }
  int pos = atomicAdd(&cursor[d], 1);
  csr_src[pos] = s;
}

// ---------- layer 1: h1 = x @ W1  (N x 64) @ (64 x 64), fused alpha dots ----------
__global__ __launch_bounds__(TPB) void k_gemm1(
    const float* __restrict__ x, const float* __restrict__ W1,
    const float* __restrict__ aS, const float* __restrict__ aD,
    float* __restrict__ h1, float* __restrict__ asrc, float* __restrict__ adst, int N) {
  __shared__ float Wl[64 * 64];
  __shared__ float xr[4][64];
  int t = threadIdx.x;
  for (int i = t; i < 64 * 64; i += TPB) Wl[i] = W1[i];
  int w = t >> 6, lane = t & 63;
  int node = blockIdx.x * 4 + w;
  if (node < N) xr[w][lane] = x[(size_t)node * 64 + lane];
  __syncthreads();
  if (node >= N) return;
  float acc = 0.f;
#pragma unroll
  for (int k = 0; k < 64; ++k) acc = fmaf(xr[w][k], Wl[k * 64 + lane], acc);
  h1[(size_t)node * 64 + lane] = acc;
  float vs = acc * aS[lane];
  float vd = acc * aD[lane];
#pragma unroll
  for (int m = 16; m >= 1; m >>= 1) {
    vs += __shfl_xor(vs, m, 64);
    vd += __shfl_xor(vd, m, 64);
  }
  if ((lane & 31) == 0) {
    asrc[node * 2 + (lane >> 5)] = vs;
    adst[node * 2 + (lane >> 5)] = vd;
  }
}

// ---------- layer 1 gather-aggregate: wave per dst node, fused norm+bias+relu ----------
__global__ __launch_bounds__(TPB) void k_gather1(
    const int* __restrict__ rowptr, const int* __restrict__ csr_src,
    const float* __restrict__ asrc, const float* __restrict__ adst,
    const float* __restrict__ h1, const float* __restrict__ b,
    float* __restrict__ out1, int N) {
  int wid = (int)((blockIdx.x * (unsigned)TPB + threadIdx.x) >> 6);
  int lane = threadIdx.x & 63;
  if (wid >= N) return;
  int h = lane >> 5;
  float ad = adst[wid * 2 + h];
  int beg = rowptr[wid], end = rowptr[wid + 1];
  float den = 0.f, acc = 0.f;
  int j = beg;
  // unroll by 2 for load-latency overlap
  for (; j + 1 < end; j += 2) {
    int s0 = csr_src[j], s1 = csr_src[j + 1];
    float v0 = asrc[s0 * 2 + h] + ad;
    float v1 = asrc[s1 * 2 + h] + ad;
    float g0 = h1[(size_t)s0 * 64 + lane];
    float g1 = h1[(size_t)s1 * 64 + lane];
    v0 = v0 > 0.f ? v0 : NEG_SLOPE * v0;
    v1 = v1 > 0.f ? v1 : NEG_SLOPE * v1;
    float e0 = __expf(v0), e1 = __expf(v1);
    den += e0 + e1;
    acc = fmaf(e0, g0, acc);
    acc = fmaf(e1, g1, acc);
  }
  if (j < end) {
    int s0 = csr_src[j];
    float v0 = asrc[s0 * 2 + h] + ad;
    v0 = v0 > 0.f ? v0 : NEG_SLOPE * v0;
    float e0 = __expf(v0);
    den += e0;
    acc = fmaf(e0, h1[(size_t)s0 * 64 + lane], acc);
  }
  float o = acc / (den + 1e-16f) + b[lane];
  out1[(size_t)wid * 64 + lane] = o > 0.f ? o : 0.f;
}

// ---------- layer 2: h2 = out1 @ W2  (N x 64) @ (64 x 32), fused alpha dots ----------
__global__ __launch_bounds__(TPB) void k_gemm2(
    const float* __restrict__ in, const float* __restrict__ W2,
    const float* __restrict__ aS, const float* __restrict__ aD,
    float* __restrict__ h2, float* __restrict__ asrc, float* __restrict__ adst, int N) {
  __shared__ float Wl[64 * 32];
  __shared__ float xr[8][64];
  int t = threadIdx.x;
  for (int i = t; i < 64 * 32; i += TPB) Wl[i] = W2[i];
  int g = t >> 5, c = t & 31;
  int node = blockIdx.x * 8 + g;
  size_t base = (size_t)blockIdx.x * 8 * 64;
  for (int i = t; i < 512; i += TPB) {
    int nn = blockIdx.x * 8 + (i >> 6);
    if (nn < N) xr[i >> 6][i & 63] = in[base + i];
  }
  __syncthreads();
  if (node >= N) return;
  float acc = 0.f;
#pragma unroll
  for (int k = 0; k < 64; ++k) acc = fmaf(xr[g][k], Wl[k * 32 + c], acc);
  h2[(size_t)node * 32 + c] = acc;
  float vs = acc * aS[c];
  float vd = acc * aD[c];
#pragma unroll
  for (int m = 16; m >= 1; m >>= 1) {
    vs += __shfl_xor(vs, m, 64);
    vd += __shfl_xor(vd, m, 64);
  }
  if (c == 0) {
    asrc[node] = vs;
    adst[node] = vd;
  }
}

// ---------- layer 2 gather-aggregate: half-wave per dst node, fused norm+bias ----------
__global__ __launch_bounds__(TPB) void k_gather2(
    const int* __restrict__ rowptr, const int* __restrict__ csr_src,
    const float* __restrict__ asrc, const float* __restrict__ adst,
    const float* __restrict__ h2, const float* __restrict__ b,
    float* __restrict__ out, int N) {
  int d = (int)((blockIdx.x * (unsigned)TPB + threadIdx.x) >> 5);
  int c = threadIdx.x & 31;
  if (d >= N) return;
  float ad = adst[d];
  int beg = rowptr[d], end = rowptr[d + 1];
  float den = 0.f, acc = 0.f;
  int j = beg;
  for (; j + 1 < end; j += 2) {
    int s0 = csr_src[j], s1 = csr_src[j + 1];
    float v0 = asrc[s0] + ad;
    float v1 = asrc[s1] + ad;
    float g0 = h2[(size_t)s0 * 32 + c];
    float g1 = h2[(size_t)s1 * 32 + c];
    v0 = v0 > 0.f ? v0 : NEG_SLOPE * v0;
    v1 = v1 > 0.f ? v1 : NEG_SLOPE * v1;
    float e0 = __expf(v0), e1 = __expf(v1);
    den += e0 + e1;
    acc = fmaf(e0, g0, acc);
    acc = fmaf(e1, g1, acc);
  }
  if (j < end) {
    int s0 = csr_src[j];
    float v0 = asrc[s0] + ad;
    v0 = v0 > 0.f ? v0 : NEG_SLOPE * v0;
    float e0 = __expf(v0);
    den += e0;
    acc = fmaf(e0, h2[(size_t)s0 * 32 + c], acc);
  }
  out[(size_t)d * 32 + c] = acc / (den + 1e-16f) + b[c];
}

extern "C" void kernel_launch(void* const* d_in, const int* in_sizes, int n_in,
                              void* d_out, int out_size, void* d_ws, size_t ws_size,
                              hipStream_t stream) {
  const float* x   = (const float*)d_in[0];
  const void*  ei  = d_in[1];
  const float* W1  = (const float*)d_in[2];
  const float* aS1 = (const float*)d_in[3];
  const float* aD1 = (const float*)d_in[4];
  const float* b1  = (const float*)d_in[5];
  const float* W2  = (const float*)d_in[6];
  const float* aS2 = (const float*)d_in[7];
  const float* aD2 = (const float*)d_in[8];
  const float* b2  = (const float*)d_in[9];
  float* out = (float*)d_out;

  int N = in_sizes[0] / 64;
  int E = in_sizes[1] / 2;
  int Etot = E + N;
  int nbN = (N + TPB - 1) / TPB;     // scan blocks over N
  int nbE = (Etot + TPB - 1) / TPB;  // blocks over edges

  float* W = (float*)d_ws;
  size_t o = 0;
  float* h1   = W + o; o += (size_t)N * 64;
  float* out1 = W + o; o += (size_t)N * 64;
  float* h2   = W + o; o += (size_t)N * 32;
  float* as1  = W + o; o += (size_t)N * 2;
  float* ad1  = W + o; o += (size_t)N * 2;
  float* as2  = W + o; o += (size_t)N;
  float* ad2  = W + o; o += (size_t)N;
  int* ip = (int*)(W + o);
  size_t io = 0;
  int* counts  = ip + io; io += N;         // zeroed each call
  int* excl    = ip + io; io += N;
  int* bsum    = ip + io; io += nbN;
  int* rowptr  = ip + io; io += N + 1;
  int* cursor  = ip + io; io += N;
  int* csr_src = ip + io; io += Etot;
  int* flag    = ip + io; io += 1;

  hipMemsetAsync(counts, 0, (size_t)N * sizeof(int), stream);
  k_detect<<<1, 1, 0, stream>>>(ei, (long long)E, flag);

  // CSR build (dst-indexed)
  k_count<<<nbE, TPB, 0, stream>>>(ei, flag, E, Etot, counts);
  k_scan1<<<nbN, TPB, 0, stream>>>(counts, excl, bsum, N);
  k_scan2<<<1, TPB, 0, stream>>>(bsum, nbN);
  k_addoff<<<nbN, TPB, 0, stream>>>(excl, bsum, rowptr, cursor, N, Etot);
  k_scatter<<<nbE, TPB, 0, stream>>>(ei, flag, E, Etot, cursor, csr_src);

  // layer 1
  k_gemm1<<<(N + 3) / 4, TPB, 0, stream>>>(x, W1, aS1, aD1, h1, as1, ad1, N);
  k_gather1<<<(N * 64 + TPB - 1) / TPB, TPB, 0, stream>>>(rowptr, csr_src, as1, ad1, h1, b1, out1, N);

  // layer 2
  k_gemm2<<<(N + 7) / 8, TPB, 0, stream>>>(out1, W2, aS2, aD2, h2, as2, ad2, N);
  k_gather2<<<(N * 32 + TPB - 1) / TPB, TPB, 0, stream>>>(rowptr, csr_src, as2, ad2, h2, b2, out, N);
}

// Round 3
// 224.758 us; speedup vs baseline: 1.9842x; 1.0920x over previous
//
#include <hip/hip_runtime.h>
#include <hip/hip_bf16.h>

#define TPB 256
#define NEG_SLOPE 0.2f

// ---------- helpers ----------
__device__ __forceinline__ int getIdx(const void* p, int is32, long long i) {
  return is32 ? ((const int*)p)[i] : (int)((const long long*)p)[i];
}

// Detect whether edge_index storage is int32 (flag=1) or int64 (flag=0).
// Node ids < 2^31; if stored int32, a u64 read combines two ids -> > 2^32.
__global__ void k_detect(const void* __restrict__ ei, long long n64, int* flag) {
  const unsigned long long* p = (const unsigned long long*)ei;
  int i = threadIdx.x;
  int is32 = (i < n64 && p[i] > 0xFFFFFFFFULL) ? 1 : 0;
  unsigned long long m = __ballot(is32);
  if (threadIdx.x == 0) *flag = (m != 0ULL) ? 1 : 0;
}

// ---------- CSR build ----------
__global__ __launch_bounds__(TPB) void k_count(
    const void* __restrict__ ei, const int* __restrict__ dflag, int E, int Etot,
    int* __restrict__ counts) {
  int e = blockIdx.x * TPB + threadIdx.x;
  if (e >= Etot) return;
  int d = (e < E) ? getIdx(ei, *dflag, (long long)E + e) : e - E;
  atomicAdd(&counts[d], 1);
}

__global__ __launch_bounds__(TPB) void k_scan1(
    const int* __restrict__ counts, int* __restrict__ excl, int* __restrict__ bsum, int N) {
  __shared__ int tmp[TPB];
  int i = blockIdx.x * TPB + threadIdx.x;
  int v = (i < N) ? counts[i] : 0;
  tmp[threadIdx.x] = v;
  __syncthreads();
  for (int off = 1; off < TPB; off <<= 1) {
    int t = (threadIdx.x >= off) ? tmp[threadIdx.x - off] : 0;
    __syncthreads();
    tmp[threadIdx.x] += t;
    __syncthreads();
  }
  if (i < N) excl[i] = tmp[threadIdx.x] - v;
  if (threadIdx.x == TPB - 1) bsum[blockIdx.x] = tmp[threadIdx.x];
}

__global__ __launch_bounds__(TPB) void k_scan2(int* __restrict__ bsum, int nb) {
  __shared__ int tmp[TPB];
  __shared__ int carrySh;
  if (threadIdx.x == 0) carrySh = 0;
  __syncthreads();
  for (int base = 0; base < nb; base += TPB) {
    int i = base + threadIdx.x;
    int v = (i < nb) ? bsum[i] : 0;
    tmp[threadIdx.x] = v;
    __syncthreads();
    for (int off = 1; off < TPB; off <<= 1) {
      int t = (threadIdx.x >= off) ? tmp[threadIdx.x - off] : 0;
      __syncthreads();
      tmp[threadIdx.x] += t;
      __syncthreads();
    }
    int carry = carrySh;
    if (i < nb) bsum[i] = carry + tmp[threadIdx.x] - v;
    __syncthreads();
    if (threadIdx.x == 0) carrySh = carry + tmp[TPB - 1];
    __syncthreads();
  }
}

__global__ __launch_bounds__(TPB) void k_addoff(
    const int* __restrict__ excl, const int* __restrict__ bsum,
    int* __restrict__ rowptr, int* __restrict__ cursor, int N, int Etot) {
  int i = blockIdx.x * TPB + threadIdx.x;
  if (i < N) {
    int v = excl[i] + bsum[blockIdx.x];
    rowptr[i] = v;
    cursor[i] = v;
  }
  if (i == 0) rowptr[N] = Etot;
}

__global__ __launch_bounds__(TPB) void k_scatter(
    const void* __restrict__ ei, const int* __restrict__ dflag, int E, int Etot,
    int* __restrict__ cursor, int* __restrict__ csr_src, int* __restrict__ csr_dst) {
  int e = blockIdx.x * TPB + threadIdx.x;
  if (e >= Etot) return;
  int s, d;
  if (e < E) {
    int f = *dflag;
    s = getIdx(ei, f, e);
    d = getIdx(ei, f, (long long)E + e);
  } else {
    s = d = e - E;
  }
  int pos = atomicAdd(&cursor[d], 1);
  csr_src[pos] = s;
  csr_dst[pos] = d;
}

// ---------- per-edge softmax weights (CSR order), layer 1 (2 heads) ----------
__global__ __launch_bounds__(TPB) void k_weights1(
    const int* __restrict__ csr_src, const int* __restrict__ csr_dst,
    const float* __restrict__ as1, const float* __restrict__ ad1,
    float* __restrict__ w1, int Etot) {
  int j = blockIdx.x * TPB + threadIdx.x;
  if (j >= Etot) return;
  int s = csr_src[j], d = csr_dst[j];
  float2 a = *(const float2*)(as1 + (size_t)s * 2);
  float2 c = *(const float2*)(ad1 + (size_t)d * 2);
  float v0 = a.x + c.x, v1 = a.y + c.y;
  v0 = v0 > 0.f ? v0 : NEG_SLOPE * v0;
  v1 = v1 > 0.f ? v1 : NEG_SLOPE * v1;
  float2 w;
  w.x = __expf(v0);
  w.y = __expf(v1);
  *(float2*)(w1 + (size_t)j * 2) = w;
}

// ---------- per-edge softmax weights, layer 2 (1 head) ----------
__global__ __launch_bounds__(TPB) void k_weights2(
    const int* __restrict__ csr_src, const int* __restrict__ csr_dst,
    const float* __restrict__ as2, const float* __restrict__ ad2,
    float* __restrict__ w2, int Etot) {
  int j = blockIdx.x * TPB + threadIdx.x;
  if (j >= Etot) return;
  float v = as2[csr_src[j]] + ad2[csr_dst[j]];
  v = v > 0.f ? v : NEG_SLOPE * v;
  w2[j] = __expf(v);
}

// ---------- layer 1: h1 = x @ W1  (N x 64) @ (64 x 64), fused alpha dots ----------
__global__ __launch_bounds__(TPB) void k_gemm1(
    const float* __restrict__ x, const float* __restrict__ W1,
    const float* __restrict__ aS, const float* __restrict__ aD,
    float* __restrict__ h1, float* __restrict__ asrc, float* __restrict__ adst, int N) {
  __shared__ float Wl[64 * 64];
  __shared__ float xr[4][64];
  int t = threadIdx.x;
  for (int i = t; i < 64 * 64; i += TPB) Wl[i] = W1[i];
  int w = t >> 6, lane = t & 63;
  int node = blockIdx.x * 4 + w;
  if (node < N) xr[w][lane] = x[(size_t)node * 64 + lane];
  __syncthreads();
  if (node >= N) return;
  float acc = 0.f;
#pragma unroll
  for (int k = 0; k < 64; ++k) acc = fmaf(xr[w][k], Wl[k * 64 + lane], acc);
  h1[(size_t)node * 64 + lane] = acc;
  float vs = acc * aS[lane];
  float vd = acc * aD[lane];
#pragma unroll
  for (int m = 16; m >= 1; m >>= 1) {
    vs += __shfl_xor(vs, m, 64);
    vd += __shfl_xor(vd, m, 64);
  }
  if ((lane & 31) == 0) {
    asrc[node * 2 + (lane >> 5)] = vs;
    adst[node * 2 + (lane >> 5)] = vd;
  }
}

// ---------- layer 1 gather: wave/node, quarter-wave/edge, float4 rows ----------
__global__ __launch_bounds__(TPB) void k_gather1(
    const int* __restrict__ rowptr, const int* __restrict__ csr_src,
    const float* __restrict__ w1, const float* __restrict__ h1,
    const float* __restrict__ b, float* __restrict__ out1, int N) {
  int wid = (int)((blockIdx.x * (unsigned)TPB + threadIdx.x) >> 6);
  int lane = threadIdx.x & 63;
  if (wid >= N) return;
  int q = lane >> 4, ql = lane & 15;
  int h = ql >> 3;  // head owning features [ql*4, ql*4+4)
  int beg = rowptr[wid], end = rowptr[wid + 1];
  float ax = 0.f, ay = 0.f, az = 0.f, aw = 0.f, den = 0.f;
  for (int j = beg + q; j < end; j += 4) {
    int s = csr_src[j];
    float w = w1[j * 2 + h];
    float4 g = *(const float4*)(h1 + (size_t)s * 64 + ql * 4);
    ax = fmaf(w, g.x, ax);
    ay = fmaf(w, g.y, ay);
    az = fmaf(w, g.z, az);
    aw = fmaf(w, g.w, aw);
    den += w;
  }
#pragma unroll
  for (int m = 16; m <= 32; m <<= 1) {
    ax += __shfl_xor(ax, m, 64);
    ay += __shfl_xor(ay, m, 64);
    az += __shfl_xor(az, m, 64);
    aw += __shfl_xor(aw, m, 64);
    den += __shfl_xor(den, m, 64);
  }
  if (q == 0) {
    float inv = 1.f / (den + 1e-16f);
    float4 bb = *(const float4*)(b + ql * 4);
    float4 o;
    o.x = fmaf(ax, inv, bb.x);
    o.y = fmaf(ay, inv, bb.y);
    o.z = fmaf(az, inv, bb.z);
    o.w = fmaf(aw, inv, bb.w);
    o.x = o.x > 0.f ? o.x : 0.f;
    o.y = o.y > 0.f ? o.y : 0.f;
    o.z = o.z > 0.f ? o.z : 0.f;
    o.w = o.w > 0.f ? o.w : 0.f;
    *(float4*)(out1 + (size_t)wid * 64 + ql * 4) = o;
  }
}

// ---------- layer 2: h2 = out1 @ W2  (N x 64) @ (64 x 32), fused alpha dots ----------
__global__ __launch_bounds__(TPB) void k_gemm2(
    const float* __restrict__ in, const float* __restrict__ W2,
    const float* __restrict__ aS, const float* __restrict__ aD,
    float* __restrict__ h2, float* __restrict__ asrc, float* __restrict__ adst, int N) {
  __shared__ float Wl[64 * 32];
  __shared__ float xr[8][64];
  int t = threadIdx.x;
  for (int i = t; i < 64 * 32; i += TPB) Wl[i] = W2[i];
  int g = t >> 5, c = t & 31;
  int node = blockIdx.x * 8 + g;
  size_t base = (size_t)blockIdx.x * 8 * 64;
  for (int i = t; i < 512; i += TPB) {
    int nn = blockIdx.x * 8 + (i >> 6);
    if (nn < N) xr[i >> 6][i & 63] = in[base + i];
  }
  __syncthreads();
  if (node >= N) return;
  float acc = 0.f;
#pragma unroll
  for (int k = 0; k < 64; ++k) acc = fmaf(xr[g][k], Wl[k * 32 + c], acc);
  h2[(size_t)node * 32 + c] = acc;
  float vs = acc * aS[c];
  float vd = acc * aD[c];
#pragma unroll
  for (int m = 16; m >= 1; m >>= 1) {
    vs += __shfl_xor(vs, m, 64);
    vd += __shfl_xor(vd, m, 64);
  }
  if (c == 0) {
    asrc[node] = vs;
    adst[node] = vd;
  }
}

// ---------- layer 2 gather: wave/node, 8-lane-group/edge, float4 rows ----------
__global__ __launch_bounds__(TPB) void k_gather2(
    const int* __restrict__ rowptr, const int* __restrict__ csr_src,
    const float* __restrict__ w2, const float* __restrict__ h2,
    const float* __restrict__ b, float* __restrict__ out, int N) {
  int wid = (int)((blockIdx.x * (unsigned)TPB + threadIdx.x) >> 6);
  int lane = threadIdx.x & 63;
  if (wid >= N) return;
  int g = lane >> 3, gl = lane & 7;
  int beg = rowptr[wid], end = rowptr[wid + 1];
  float ax = 0.f, ay = 0.f, az = 0.f, aw = 0.f, den = 0.f;
  for (int j = beg + g; j < end; j += 8) {
    int s = csr_src[j];
    float w = w2[j];
    float4 v = *(const float4*)(h2 + (size_t)s * 32 + gl * 4);
    ax = fmaf(w, v.x, ax);
    ay = fmaf(w, v.y, ay);
    az = fmaf(w, v.z, az);
    aw = fmaf(w, v.w, aw);
    den += w;
  }
#pragma unroll
  for (int m = 8; m <= 32; m <<= 1) {
    ax += __shfl_xor(ax, m, 64);
    ay += __shfl_xor(ay, m, 64);
    az += __shfl_xor(az, m, 64);
    aw += __shfl_xor(aw, m, 64);
    den += __shfl_xor(den, m, 64);
  }
  if (g == 0) {
    float inv = 1.f / (den + 1e-16f);
    float4 bb = *(const float4*)(b + gl * 4);
    float4 o;
    o.x = fmaf(ax, inv, bb.x);
    o.y = fmaf(ay, inv, bb.y);
    o.z = fmaf(az, inv, bb.z);
    o.w = fmaf(aw, inv, bb.w);
    *(float4*)(out + (size_t)wid * 32 + gl * 4) = o;
  }
}

extern "C" void kernel_launch(void* const* d_in, const int* in_sizes, int n_in,
                              void* d_out, int out_size, void* d_ws, size_t ws_size,
                              hipStream_t stream) {
  const float* x   = (const float*)d_in[0];
  const void*  ei  = d_in[1];
  const float* W1  = (const float*)d_in[2];
  const float* aS1 = (const float*)d_in[3];
  const float* aD1 = (const float*)d_in[4];
  const float* b1  = (const float*)d_in[5];
  const float* W2  = (const float*)d_in[6];
  const float* aS2 = (const float*)d_in[7];
  const float* aD2 = (const float*)d_in[8];
  const float* b2  = (const float*)d_in[9];
  float* out = (float*)d_out;

  int N = in_sizes[0] / 64;
  int E = in_sizes[1] / 2;
  int Etot = E + N;
  int nbN = (N + TPB - 1) / TPB;
  int nbE = (Etot + TPB - 1) / TPB;

  float* W = (float*)d_ws;
  size_t o = 0;
  // Region A: h1 (alive gemm1->gather1), then reused for w2 (weights2->gather2)
  float* h1 = W + o;
  float* w2 = h1;                   // alias: disjoint lifetimes
  o += (size_t)N * 64;
  // Region B: w1 (weights1->gather1) shares with h2 (gemm2->gather2)
  size_t regB = (size_t)(2 * Etot > N * 32 ? 2 * Etot : N * 32);
  float* w1 = W + o;
  float* h2 = W + o;
  o += regB;
  float* out1 = W + o; o += (size_t)N * 64;
  float* as1  = W + o; o += (size_t)N * 2;
  float* ad1  = W + o; o += (size_t)N * 2;
  float* as2  = W + o; o += (size_t)N;
  float* ad2  = W + o; o += (size_t)N;
  int* ip = (int*)(W + o);
  size_t io = 0;
  int* counts  = ip + io; io += N;
  int* excl    = ip + io; io += N;
  int* bsum    = ip + io; io += nbN;
  int* rowptr  = ip + io; io += N + 1;
  int* cursor  = ip + io; io += N;
  int* csr_src = ip + io; io += Etot;
  int* csr_dst = ip + io; io += Etot;
  int* flag    = ip + io; io += 1;

  hipMemsetAsync(counts, 0, (size_t)N * sizeof(int), stream);
  k_detect<<<1, 64, 0, stream>>>(ei, (long long)E, flag);

  // CSR build (dst-indexed)
  k_count<<<nbE, TPB, 0, stream>>>(ei, flag, E, Etot, counts);
  k_scan1<<<nbN, TPB, 0, stream>>>(counts, excl, bsum, N);
  k_scan2<<<1, TPB, 0, stream>>>(bsum, nbN);
  k_addoff<<<nbN, TPB, 0, stream>>>(excl, bsum, rowptr, cursor, N, Etot);
  k_scatter<<<nbE, TPB, 0, stream>>>(ei, flag, E, Etot, cursor, csr_src, csr_dst);

  // layer 1
  k_gemm1<<<(N + 3) / 4, TPB, 0, stream>>>(x, W1, aS1, aD1, h1, as1, ad1, N);
  k_weights1<<<nbE, TPB, 0, stream>>>(csr_src, csr_dst, as1, ad1, w1, Etot);
  k_gather1<<<(N * 64 + TPB - 1) / TPB, TPB, 0, stream>>>(rowptr, csr_src, w1, h1, b1, out1, N);

  // layer 2
  k_gemm2<<<(N + 7) / 8, TPB, 0, stream>>>(out1, W2, aS2, aD2, h2, as2, ad2, N);
  k_weights2<<<nbE, TPB, 0, stream>>>(csr_src, csr_dst, as2, ad2, w2, Etot);
  k_gather2<<<(N * 64 + TPB - 1) / TPB, TPB, 0, stream>>>(rowptr, csr_src, w2, h2, b2, out, N);
}

// Round 4
// 213.501 us; speedup vs baseline: 2.0889x; 1.0527x over previous
//
#include <hip/hip_runtime.h>
#include <hip/hip_bf16.h>

#define TPB 256
#define NEG_SLOPE 0.2f

// ---------- helpers ----------
__device__ __forceinline__ int getIdx(const void* p, int is32, long long i) {
  return is32 ? ((const int*)p)[i] : (int)((const long long*)p)[i];
}

// Detect whether edge_index storage is int32 (flag=1) or int64 (flag=0).
// Node ids < 2^31; if stored int32, a u64 read combines two ids -> > 2^32.
__global__ void k_detect(const void* __restrict__ ei, long long n64, int* flag) {
  const unsigned long long* p = (const unsigned long long*)ei;
  int i = threadIdx.x;
  int is32 = (i < n64 && p[i] > 0xFFFFFFFFULL) ? 1 : 0;
  unsigned long long m = __ballot(is32);
  if (threadIdx.x == 0) *flag = (m != 0ULL) ? 1 : 0;
}

// ---------- CSR build ----------
__global__ __launch_bounds__(TPB) void k_count(
    const void* __restrict__ ei, const int* __restrict__ dflag, int E, int Etot,
    int* __restrict__ counts) {
  int e = blockIdx.x * TPB + threadIdx.x;
  if (e >= Etot) return;
  int d = (e < E) ? getIdx(ei, *dflag, (long long)E + e) : e - E;
  atomicAdd(&counts[d], 1);
}

__global__ __launch_bounds__(TPB) void k_scan1(
    const int* __restrict__ counts, int* __restrict__ excl, int* __restrict__ bsum, int N) {
  __shared__ int tmp[TPB];
  int i = blockIdx.x * TPB + threadIdx.x;
  int v = (i < N) ? counts[i] : 0;
  tmp[threadIdx.x] = v;
  __syncthreads();
  for (int off = 1; off < TPB; off <<= 1) {
    int t = (threadIdx.x >= off) ? tmp[threadIdx.x - off] : 0;
    __syncthreads();
    tmp[threadIdx.x] += t;
    __syncthreads();
  }
  if (i < N) excl[i] = tmp[threadIdx.x] - v;
  if (threadIdx.x == TPB - 1) bsum[blockIdx.x] = tmp[threadIdx.x];
}

__global__ __launch_bounds__(TPB) void k_scan2(int* __restrict__ bsum, int nb) {
  __shared__ int tmp[TPB];
  __shared__ int carrySh;
  if (threadIdx.x == 0) carrySh = 0;
  __syncthreads();
  for (int base = 0; base < nb; base += TPB) {
    int i = base + threadIdx.x;
    int v = (i < nb) ? bsum[i] : 0;
    tmp[threadIdx.x] = v;
    __syncthreads();
    for (int off = 1; off < TPB; off <<= 1) {
      int t = (threadIdx.x >= off) ? tmp[threadIdx.x - off] : 0;
      __syncthreads();
      tmp[threadIdx.x] += t;
      __syncthreads();
    }
    int carry = carrySh;
    if (i < nb) bsum[i] = carry + tmp[threadIdx.x] - v;
    __syncthreads();
    if (threadIdx.x == 0) carrySh = carry + tmp[TPB - 1];
    __syncthreads();
  }
}

__global__ __launch_bounds__(TPB) void k_addoff(
    const int* __restrict__ excl, const int* __restrict__ bsum,
    int* __restrict__ rowptr, int* __restrict__ cursor, int N, int Etot) {
  int i = blockIdx.x * TPB + threadIdx.x;
  if (i < N) {
    int v = excl[i] + bsum[blockIdx.x];
    rowptr[i] = v;
    cursor[i] = v;
  }
  if (i == 0) rowptr[N] = Etot;
}

__global__ __launch_bounds__(TPB) void k_scatter(
    const void* __restrict__ ei, const int* __restrict__ dflag, int E, int Etot,
    int* __restrict__ cursor, int* __restrict__ csr_src) {
  int e = blockIdx.x * TPB + threadIdx.x;
  if (e >= Etot) return;
  int s, d;
  if (e < E) {
    int f = *dflag;
    s = getIdx(ei, f, e);
    d = getIdx(ei, f, (long long)E + e);
  } else {
    s = d = e - E;
  }
  int pos = atomicAdd(&cursor[d], 1);
  csr_src[pos] = s;
}

// ---------- layer 1: h1 = x @ W1  (N x 64) @ (64 x 64), fused alpha dots ----------
__global__ __launch_bounds__(TPB) void k_gemm1(
    const float* __restrict__ x, const float* __restrict__ W1,
    const float* __restrict__ aS, const float* __restrict__ aD,
    float* __restrict__ h1, float* __restrict__ asrc, float* __restrict__ adst, int N) {
  __shared__ float Wl[64 * 64];
  __shared__ float xr[4][64];
  int t = threadIdx.x;
  for (int i = t; i < 64 * 64; i += TPB) Wl[i] = W1[i];
  int w = t >> 6, lane = t & 63;
  int node = blockIdx.x * 4 + w;
  if (node < N) xr[w][lane] = x[(size_t)node * 64 + lane];
  __syncthreads();
  if (node >= N) return;
  float acc = 0.f;
#pragma unroll
  for (int k = 0; k < 64; ++k) acc = fmaf(xr[w][k], Wl[k * 64 + lane], acc);
  h1[(size_t)node * 64 + lane] = acc;
  float vs = acc * aS[lane];
  float vd = acc * aD[lane];
#pragma unroll
  for (int m = 16; m >= 1; m >>= 1) {
    vs += __shfl_xor(vs, m, 64);
    vd += __shfl_xor(vd, m, 64);
  }
  if ((lane & 31) == 0) {
    asrc[node * 2 + (lane >> 5)] = vs;
    adst[node * 2 + (lane >> 5)] = vd;
  }
}

// ---------- layer 1 gather: wave/node, quarter-wave/edge, inline softmax weight ----------
__global__ __launch_bounds__(TPB) void k_gather1(
    const int* __restrict__ rowptr, const int* __restrict__ csr_src,
    const float* __restrict__ as1, const float* __restrict__ ad1,
    const float* __restrict__ h1, const float* __restrict__ b,
    float* __restrict__ out1, int N) {
  int wid = (int)((blockIdx.x * (unsigned)TPB + threadIdx.x) >> 6);
  int lane = threadIdx.x & 63;
  if (wid >= N) return;
  int q = lane >> 4, ql = lane & 15;
  int h = ql >> 3;  // head owning features [ql*4, ql*4+4)
  float ad = ad1[wid * 2 + h];
  int beg = rowptr[wid], end = rowptr[wid + 1];
  float ax = 0.f, ay = 0.f, az = 0.f, aw = 0.f, den = 0.f;
  for (int j = beg + q; j < end; j += 4) {
    int s = csr_src[j];
    float v = as1[s * 2 + h] + ad;
    float4 g = *(const float4*)(h1 + (size_t)s * 64 + ql * 4);
    v = v > 0.f ? v : NEG_SLOPE * v;
    float w = __expf(v);
    ax = fmaf(w, g.x, ax);
    ay = fmaf(w, g.y, ay);
    az = fmaf(w, g.z, az);
    aw = fmaf(w, g.w, aw);
    den += w;
  }
#pragma unroll
  for (int m = 16; m <= 32; m <<= 1) {
    ax += __shfl_xor(ax, m, 64);
    ay += __shfl_xor(ay, m, 64);
    az += __shfl_xor(az, m, 64);
    aw += __shfl_xor(aw, m, 64);
    den += __shfl_xor(den, m, 64);
  }
  if (q == 0) {
    float inv = 1.f / (den + 1e-16f);
    float4 bb = *(const float4*)(b + ql * 4);
    float4 o;
    o.x = fmaf(ax, inv, bb.x);
    o.y = fmaf(ay, inv, bb.y);
    o.z = fmaf(az, inv, bb.z);
    o.w = fmaf(aw, inv, bb.w);
    o.x = o.x > 0.f ? o.x : 0.f;
    o.y = o.y > 0.f ? o.y : 0.f;
    o.z = o.z > 0.f ? o.z : 0.f;
    o.w = o.w > 0.f ? o.w : 0.f;
    *(float4*)(out1 + (size_t)wid * 64 + ql * 4) = o;
  }
}

// ---------- layer 2: h2 = out1 @ W2  (N x 64) @ (64 x 32), fused alpha dots ----------
__global__ __launch_bounds__(TPB) void k_gemm2(
    const float* __restrict__ in, const float* __restrict__ W2,
    const float* __restrict__ aS, const float* __restrict__ aD,
    float* __restrict__ h2, float* __restrict__ asrc, float* __restrict__ adst, int N) {
  __shared__ float Wl[64 * 32];
  __shared__ float xr[8][64];
  int t = threadIdx.x;
  for (int i = t; i < 64 * 32; i += TPB) Wl[i] = W2[i];
  int g = t >> 5, c = t & 31;
  int node = blockIdx.x * 8 + g;
  size_t base = (size_t)blockIdx.x * 8 * 64;
  for (int i = t; i < 512; i += TPB) {
    int nn = blockIdx.x * 8 + (i >> 6);
    if (nn < N) xr[i >> 6][i & 63] = in[base + i];
  }
  __syncthreads();
  if (node >= N) return;
  float acc = 0.f;
#pragma unroll
  for (int k = 0; k < 64; ++k) acc = fmaf(xr[g][k], Wl[k * 32 + c], acc);
  h2[(size_t)node * 32 + c] = acc;
  float vs = acc * aS[c];
  float vd = acc * aD[c];
#pragma unroll
  for (int m = 16; m >= 1; m >>= 1) {
    vs += __shfl_xor(vs, m, 64);
    vd += __shfl_xor(vd, m, 64);
  }
  if (c == 0) {
    asrc[node] = vs;
    adst[node] = vd;
  }
}

// ---------- layer 2 gather: wave/node, 8-lane-group/edge, inline softmax weight ----------
__global__ __launch_bounds__(TPB) void k_gather2(
    const int* __restrict__ rowptr, const int* __restrict__ csr_src,
    const float* __restrict__ as2, const float* __restrict__ ad2,
    const float* __restrict__ h2, const float* __restrict__ b,
    float* __restrict__ out, int N) {
  int wid = (int)((blockIdx.x * (unsigned)TPB + threadIdx.x) >> 6);
  int lane = threadIdx.x & 63;
  if (wid >= N) return;
  int g = lane >> 3, gl = lane & 7;
  float ad = ad2[wid];
  int beg = rowptr[wid], end = rowptr[wid + 1];
  float ax = 0.f, ay = 0.f, az = 0.f, aw = 0.f, den = 0.f;
  for (int j = beg + g; j < end; j += 8) {
    int s = csr_src[j];
    float v = as2[s] + ad;
    float4 v4 = *(const float4*)(h2 + (size_t)s * 32 + gl * 4);
    v = v > 0.f ? v : NEG_SLOPE * v;
    float w = __expf(v);
    ax = fmaf(w, v4.x, ax);
    ay = fmaf(w, v4.y, ay);
    az = fmaf(w, v4.z, az);
    aw = fmaf(w, v4.w, aw);
    den += w;
  }
#pragma unroll
  for (int m = 8; m <= 32; m <<= 1) {
    ax += __shfl_xor(ax, m, 64);
    ay += __shfl_xor(ay, m, 64);
    az += __shfl_xor(az, m, 64);
    aw += __shfl_xor(aw, m, 64);
    den += __shfl_xor(den, m, 64);
  }
  if (g == 0) {
    float inv = 1.f / (den + 1e-16f);
    float4 bb = *(const float4*)(b + gl * 4);
    float4 o;
    o.x = fmaf(ax, inv, bb.x);
    o.y = fmaf(ay, inv, bb.y);
    o.z = fmaf(az, inv, bb.z);
    o.w = fmaf(aw, inv, bb.w);
    *(float4*)(out + (size_t)wid * 32 + gl * 4) = o;
  }
}

extern "C" void kernel_launch(void* const* d_in, const int* in_sizes, int n_in,
                              void* d_out, int out_size, void* d_ws, size_t ws_size,
                              hipStream_t stream) {
  const float* x   = (const float*)d_in[0];
  const void*  ei  = d_in[1];
  const float* W1  = (const float*)d_in[2];
  const float* aS1 = (const float*)d_in[3];
  const float* aD1 = (const float*)d_in[4];
  const float* b1  = (const float*)d_in[5];
  const float* W2  = (const float*)d_in[6];
  const float* aS2 = (const float*)d_in[7];
  const float* aD2 = (const float*)d_in[8];
  const float* b2  = (const float*)d_in[9];
  float* out = (float*)d_out;

  int N = in_sizes[0] / 64;
  int E = in_sizes[1] / 2;
  int Etot = E + N;
  int nbN = (N + TPB - 1) / TPB;
  int nbE = (Etot + TPB - 1) / TPB;

  float* W = (float*)d_ws;
  size_t o = 0;
  float* h1   = W + o; o += (size_t)N * 64;
  float* out1 = W + o; o += (size_t)N * 64;
  float* h2   = W + o; o += (size_t)N * 32;
  float* as1  = W + o; o += (size_t)N * 2;
  float* ad1  = W + o; o += (size_t)N * 2;
  float* as2  = W + o; o += (size_t)N;
  float* ad2  = W + o; o += (size_t)N;
  int* ip = (int*)(W + o);
  size_t io = 0;
  int* counts  = ip + io; io += N;
  int* excl    = ip + io; io += N;
  int* bsum    = ip + io; io += nbN;
  int* rowptr  = ip + io; io += N + 1;
  int* cursor  = ip + io; io += N;
  int* csr_src = ip + io; io += Etot;
  int* flag    = ip + io; io += 1;

  hipMemsetAsync(counts, 0, (size_t)N * sizeof(int), stream);
  k_detect<<<1, 64, 0, stream>>>(ei, (long long)E, flag);

  // CSR build (dst-indexed)
  k_count<<<nbE, TPB, 0, stream>>>(ei, flag, E, Etot, counts);
  k_scan1<<<nbN, TPB, 0, stream>>>(counts, excl, bsum, N);
  k_scan2<<<1, TPB, 0, stream>>>(bsum, nbN);
  k_addoff<<<nbN, TPB, 0, stream>>>(excl, bsum, rowptr, cursor, N, Etot);
  k_scatter<<<nbE, TPB, 0, stream>>>(ei, flag, E, Etot, cursor, csr_src);

  // layer 1
  k_gemm1<<<(N + 3) / 4, TPB, 0, stream>>>(x, W1, aS1, aD1, h1, as1, ad1, N);
  k_gather1<<<(N * 64 + TPB - 1) / TPB, TPB, 0, stream>>>(rowptr, csr_src, as1, ad1, h1, b1, out1, N);

  // layer 2
  k_gemm2<<<(N + 7) / 8, TPB, 0, stream>>>(out1, W2, aS2, aD2, h2, as2, ad2, N);
  k_gather2<<<(N * 64 + TPB - 1) / TPB, TPB, 0, stream>>>(rowptr, csr_src, as2, ad2, h2, b2, out, N);
}

// Round 5
// 180.951 us; speedup vs baseline: 2.4646x; 1.1799x over previous
//
#include <hip/hip_runtime.h>
#include <hip/hip_bf16.h>

#define TPB 256
#define NEG_SLOPE 0.2f
#define B1 256          // blocks for hist/place passes
#define MAXNB 512       // max dst-buckets (N <= 65536)

// ---------- helpers ----------
__device__ __forceinline__ int getIdx(const void* p, int is32, long long i) {
  return is32 ? ((const int*)p)[i] : (int)((const long long*)p)[i];
}

// Detect whether edge_index storage is int32 (flag=1) or int64 (flag=0).
__global__ void k_detect(const void* __restrict__ ei, long long n64, int* flag) {
  const unsigned long long* p = (const unsigned long long*)ei;
  int i = threadIdx.x;
  int is32 = (i < n64 && p[i] > 0xFFFFFFFFULL) ? 1 : 0;
  unsigned long long m = __ballot(is32);
  if (threadIdx.x == 0) *flag = (m != 0ULL) ? 1 : 0;
}

// ---------- CSR build, stage 1: per-block bucket histograms (LDS only) ----------
__global__ __launch_bounds__(TPB) void k_histA(
    const void* __restrict__ ei, const int* __restrict__ dflag, int E, int Etot,
    int* __restrict__ histA, int NB, int CH) {
  __shared__ int lh[MAXNB];
  int b = blockIdx.x, tid = threadIdx.x;
  for (int i = tid; i < NB; i += TPB) lh[i] = 0;
  __syncthreads();
  int f = *dflag;
  int beg = b * CH, end = min(beg + CH, Etot);
  for (int e = beg + tid; e < end; e += TPB) {
    int d = (e < E) ? getIdx(ei, f, (long long)E + e) : e - E;
    atomicAdd(&lh[d >> 7], 1);
  }
  __syncthreads();
  for (int i = tid; i < NB; i += TPB) histA[i * B1 + b] = lh[i];
}

// ---------- stage 2: prefix bases (single block; NB <= 512) ----------
__global__ __launch_bounds__(512) void k_scanA(
    const int* __restrict__ histA, int* __restrict__ blockBase,
    int* __restrict__ bucketBase, int NB, int Etot) {
  __shared__ int sh[512];
  int t = threadIdx.x;
  int tot = 0;
  if (t < NB) {
    int base = t * B1;
    int run = 0;
    for (int b = 0; b < B1; ++b) {
      int v = histA[base + b];
      blockBase[base + b] = run;   // intra-bucket exclusive prefix over blocks
      run += v;
    }
    tot = run;
  }
  sh[t] = tot;
  __syncthreads();
  for (int off = 1; off < 512; off <<= 1) {
    int v = (t >= off) ? sh[t - off] : 0;
    __syncthreads();
    sh[t] += v;
    __syncthreads();
  }
  if (t < NB) bucketBase[t] = sh[t] - tot;  // exclusive
  if (t == 511) bucketBase[NB] = sh[511];   // == Etot
}

// ---------- stage 3: place (src,dst) pairs grouped by bucket (LDS cursors) ----------
__global__ __launch_bounds__(TPB) void k_placeB(
    const void* __restrict__ ei, const int* __restrict__ dflag, int E, int Etot,
    const int* __restrict__ blockBase, const int* __restrict__ bucketBase,
    int2* __restrict__ pairs, int NB, int CH) {
  __shared__ int cur[MAXNB];
  int b = blockIdx.x, tid = threadIdx.x;
  for (int i = tid; i < NB; i += TPB) cur[i] = blockBase[i * B1 + b] + bucketBase[i];
  __syncthreads();
  int f = *dflag;
  int beg = b * CH, end = min(beg + CH, Etot);
  for (int e = beg + tid; e < end; e += TPB) {
    int s, d;
    if (e < E) {
      s = getIdx(ei, f, e);
      d = getIdx(ei, f, (long long)E + e);
    } else {
      s = d = e - E;
    }
    int pos = atomicAdd(&cur[d >> 7], 1);
    pairs[pos] = make_int2(s, d);
  }
}

// ---------- stage 4: per-bucket dst counts -> rowptr (LDS hist + LDS scan) ----------
__global__ __launch_bounds__(TPB) void k_rowptr(
    const int2* __restrict__ pairs, const int* __restrict__ bucketBase,
    int* __restrict__ rowptr, int N, int Etot) {
  int g = blockIdx.x, tid = threadIdx.x;
  __shared__ int cnt[128];
  __shared__ int sc[128];
  if (tid < 128) cnt[tid] = 0;
  __syncthreads();
  int beg = bucketBase[g], end = bucketBase[g + 1];
  for (int j = beg + tid; j < end; j += TPB) atomicAdd(&cnt[pairs[j].y & 127], 1);
  __syncthreads();
  if (tid < 128) sc[tid] = cnt[tid];
  __syncthreads();
  for (int off = 1; off < 128; off <<= 1) {
    int v = (tid >= off && tid < 128) ? sc[tid - off] : 0;
    __syncthreads();
    if (tid < 128) sc[tid] += v;
    __syncthreads();
  }
  int base = g << 7;
  int nd = N - base; if (nd > 128) nd = 128;
  if (tid < nd) rowptr[base + tid] = beg + sc[tid] - cnt[tid];
  if (g == 0 && tid == 0) rowptr[N] = Etot;
}

// ---------- stage 5: final csr_src placement (single-owner regions) ----------
__global__ __launch_bounds__(TPB) void k_placeD(
    const int2* __restrict__ pairs, const int* __restrict__ bucketBase,
    const int* __restrict__ rowptr, int* __restrict__ csr_src, int N) {
  int g = blockIdx.x, tid = threadIdx.x;
  __shared__ int cur[128];
  int base = g << 7;
  int nd = N - base; if (nd > 128) nd = 128;
  if (tid < nd) cur[tid] = rowptr[base + tid];
  __syncthreads();
  int beg = bucketBase[g], end = bucketBase[g + 1];
  for (int j = beg + tid; j < end; j += TPB) {
    int2 p = pairs[j];
    int pos = atomicAdd(&cur[p.y & 127], 1);
    csr_src[pos] = p.x;
  }
}

// ---------- layer 1: h1 = x @ W1  (N x 64) @ (64 x 64), fused alpha dots ----------
__global__ __launch_bounds__(TPB) void k_gemm1(
    const float* __restrict__ x, const float* __restrict__ W1,
    const float* __restrict__ aS, const float* __restrict__ aD,
    float* __restrict__ h1, float* __restrict__ asrc, float* __restrict__ adst, int N) {
  __shared__ float Wl[64 * 64];
  __shared__ float xr[4][64];
  int t = threadIdx.x;
  for (int i = t; i < 64 * 64; i += TPB) Wl[i] = W1[i];
  int w = t >> 6, lane = t & 63;
  int node = blockIdx.x * 4 + w;
  if (node < N) xr[w][lane] = x[(size_t)node * 64 + lane];
  __syncthreads();
  if (node >= N) return;
  float acc = 0.f;
#pragma unroll
  for (int k = 0; k < 64; ++k) acc = fmaf(xr[w][k], Wl[k * 64 + lane], acc);
  h1[(size_t)node * 64 + lane] = acc;
  float vs = acc * aS[lane];
  float vd = acc * aD[lane];
#pragma unroll
  for (int m = 16; m >= 1; m >>= 1) {
    vs += __shfl_xor(vs, m, 64);
    vd += __shfl_xor(vd, m, 64);
  }
  if ((lane & 31) == 0) {
    asrc[node * 2 + (lane >> 5)] = vs;
    adst[node * 2 + (lane >> 5)] = vd;
  }
}

// ---------- layer 1 gather: wave/node, quarter-wave/edge, inline softmax weight ----------
__global__ __launch_bounds__(TPB) void k_gather1(
    const int* __restrict__ rowptr, const int* __restrict__ csr_src,
    const float* __restrict__ as1, const float* __restrict__ ad1,
    const float* __restrict__ h1, const float* __restrict__ b,
    float* __restrict__ out1, int N) {
  int wid = (int)((blockIdx.x * (unsigned)TPB + threadIdx.x) >> 6);
  int lane = threadIdx.x & 63;
  if (wid >= N) return;
  int q = lane >> 4, ql = lane & 15;
  int h = ql >> 3;  // head owning features [ql*4, ql*4+4)
  float ad = ad1[wid * 2 + h];
  int beg = rowptr[wid], end = rowptr[wid + 1];
  float ax = 0.f, ay = 0.f, az = 0.f, aw = 0.f, den = 0.f;
  for (int j = beg + q; j < end; j += 4) {
    int s = csr_src[j];
    float v = as1[s * 2 + h] + ad;
    float4 g = *(const float4*)(h1 + (size_t)s * 64 + ql * 4);
    v = v > 0.f ? v : NEG_SLOPE * v;
    float w = __expf(v);
    ax = fmaf(w, g.x, ax);
    ay = fmaf(w, g.y, ay);
    az = fmaf(w, g.z, az);
    aw = fmaf(w, g.w, aw);
    den += w;
  }
#pragma unroll
  for (int m = 16; m <= 32; m <<= 1) {
    ax += __shfl_xor(ax, m, 64);
    ay += __shfl_xor(ay, m, 64);
    az += __shfl_xor(az, m, 64);
    aw += __shfl_xor(aw, m, 64);
    den += __shfl_xor(den, m, 64);
  }
  if (q == 0) {
    float inv = 1.f / (den + 1e-16f);
    float4 bb = *(const float4*)(b + ql * 4);
    float4 o;
    o.x = fmaf(ax, inv, bb.x);
    o.y = fmaf(ay, inv, bb.y);
    o.z = fmaf(az, inv, bb.z);
    o.w = fmaf(aw, inv, bb.w);
    o.x = o.x > 0.f ? o.x : 0.f;
    o.y = o.y > 0.f ? o.y : 0.f;
    o.z = o.z > 0.f ? o.z : 0.f;
    o.w = o.w > 0.f ? o.w : 0.f;
    *(float4*)(out1 + (size_t)wid * 64 + ql * 4) = o;
  }
}

// ---------- layer 2: h2 = out1 @ W2  (N x 64) @ (64 x 32), fused alpha dots ----------
__global__ __launch_bounds__(TPB) void k_gemm2(
    const float* __restrict__ in, const float* __restrict__ W2,
    const float* __restrict__ aS, const float* __restrict__ aD,
    float* __restrict__ h2, float* __restrict__ asrc, float* __restrict__ adst, int N) {
  __shared__ float Wl[64 * 32];
  __shared__ float xr[8][64];
  int t = threadIdx.x;
  for (int i = t; i < 64 * 32; i += TPB) Wl[i] = W2[i];
  int g = t >> 5, c = t & 31;
  int node = blockIdx.x * 8 + g;
  size_t base = (size_t)blockIdx.x * 8 * 64;
  for (int i = t; i < 512; i += TPB) {
    int nn = blockIdx.x * 8 + (i >> 6);
    if (nn < N) xr[i >> 6][i & 63] = in[base + i];
  }
  __syncthreads();
  if (node >= N) return;
  float acc = 0.f;
#pragma unroll
  for (int k = 0; k < 64; ++k) acc = fmaf(xr[g][k], Wl[k * 32 + c], acc);
  h2[(size_t)node * 32 + c] = acc;
  float vs = acc * aS[c];
  float vd = acc * aD[c];
#pragma unroll
  for (int m = 16; m >= 1; m >>= 1) {
    vs += __shfl_xor(vs, m, 64);
    vd += __shfl_xor(vd, m, 64);
  }
  if (c == 0) {
    asrc[node] = vs;
    adst[node] = vd;
  }
}

// ---------- layer 2 gather: wave/node, 8-lane-group/edge, inline softmax weight ----------
__global__ __launch_bounds__(TPB) void k_gather2(
    const int* __restrict__ rowptr, const int* __restrict__ csr_src,
    const float* __restrict__ as2, const float* __restrict__ ad2,
    const float* __restrict__ h2, const float* __restrict__ b,
    float* __restrict__ out, int N) {
  int wid = (int)((blockIdx.x * (unsigned)TPB + threadIdx.x) >> 6);
  int lane = threadIdx.x & 63;
  if (wid >= N) return;
  int g = lane >> 3, gl = lane & 7;
  float ad = ad2[wid];
  int beg = rowptr[wid], end = rowptr[wid + 1];
  float ax = 0.f, ay = 0.f, az = 0.f, aw = 0.f, den = 0.f;
  for (int j = beg + g; j < end; j += 8) {
    int s = csr_src[j];
    float v = as2[s] + ad;
    float4 v4 = *(const float4*)(h2 + (size_t)s * 32 + gl * 4);
    v = v > 0.f ? v : NEG_SLOPE * v;
    float w = __expf(v);
    ax = fmaf(w, v4.x, ax);
    ay = fmaf(w, v4.y, ay);
    az = fmaf(w, v4.z, az);
    aw = fmaf(w, v4.w, aw);
    den += w;
  }
#pragma unroll
  for (int m = 8; m <= 32; m <<= 1) {
    ax += __shfl_xor(ax, m, 64);
    ay += __shfl_xor(ay, m, 64);
    az += __shfl_xor(az, m, 64);
    aw += __shfl_xor(aw, m, 64);
    den += __shfl_xor(den, m, 64);
  }
  if (g == 0) {
    float inv = 1.f / (den + 1e-16f);
    float4 bb = *(const float4*)(b + gl * 4);
    float4 o;
    o.x = fmaf(ax, inv, bb.x);
    o.y = fmaf(ay, inv, bb.y);
    o.z = fmaf(az, inv, bb.z);
    o.w = fmaf(aw, inv, bb.w);
    *(float4*)(out + (size_t)wid * 32 + gl * 4) = o;
  }
}

extern "C" void kernel_launch(void* const* d_in, const int* in_sizes, int n_in,
                              void* d_out, int out_size, void* d_ws, size_t ws_size,
                              hipStream_t stream) {
  const float* x   = (const float*)d_in[0];
  const void*  ei  = d_in[1];
  const float* W1  = (const float*)d_in[2];
  const float* aS1 = (const float*)d_in[3];
  const float* aD1 = (const float*)d_in[4];
  const float* b1  = (const float*)d_in[5];
  const float* W2  = (const float*)d_in[6];
  const float* aS2 = (const float*)d_in[7];
  const float* aD2 = (const float*)d_in[8];
  const float* b2  = (const float*)d_in[9];
  float* out = (float*)d_out;

  int N = in_sizes[0] / 64;
  int E = in_sizes[1] / 2;
  int Etot = E + N;
  int NB = (N + 127) >> 7;              // dst buckets of 128
  int CH = (Etot + B1 - 1) / B1;        // edges per hist/place block

  float* W = (float*)d_ws;
  size_t o = 0;
  float* h1   = W + o; o += (size_t)N * 64;
  float* out1 = W + o; o += (size_t)N * 64;
  // pairs (int2, Etot) shares storage with h2 (N*32 floats): disjoint lifetimes
  size_t regB = (size_t)(2 * Etot > N * 32 ? 2 * Etot : N * 32);
  int2* pairs = (int2*)(W + o);
  float* h2   = W + o;
  o += regB;
  float* as1  = W + o; o += (size_t)N * 2;
  float* ad1  = W + o; o += (size_t)N * 2;
  float* as2  = W + o; o += (size_t)N;
  float* ad2  = W + o; o += (size_t)N;
  int* ip = (int*)(W + o);
  size_t io = 0;
  int* histA      = ip + io; io += (size_t)NB * B1;
  int* blockBase  = ip + io; io += (size_t)NB * B1;
  int* bucketBase = ip + io; io += NB + 1;
  int* rowptr     = ip + io; io += N + 1;
  int* csr_src    = ip + io; io += Etot;
  int* flag       = ip + io; io += 1;

  k_detect<<<1, 64, 0, stream>>>(ei, (long long)E, flag);

  // CSR build: LDS-binned counting sort, no global return-atomics
  k_histA<<<B1, TPB, 0, stream>>>(ei, flag, E, Etot, histA, NB, CH);
  k_scanA<<<1, 512, 0, stream>>>(histA, blockBase, bucketBase, NB, Etot);
  k_placeB<<<B1, TPB, 0, stream>>>(ei, flag, E, Etot, blockBase, bucketBase, pairs, NB, CH);
  k_rowptr<<<NB, TPB, 0, stream>>>(pairs, bucketBase, rowptr, N, Etot);
  k_placeD<<<NB, TPB, 0, stream>>>(pairs, bucketBase, rowptr, csr_src, N);

  // layer 1
  k_gemm1<<<(N + 3) / 4, TPB, 0, stream>>>(x, W1, aS1, aD1, h1, as1, ad1, N);
  k_gather1<<<(N * 64 + TPB - 1) / TPB, TPB, 0, stream>>>(rowptr, csr_src, as1, ad1, h1, b1, out1, N);

  // layer 2
  k_gemm2<<<(N + 7) / 8, TPB, 0, stream>>>(out1, W2, aS2, aD2, h2, as2, ad2, N);
  k_gather2<<<(N * 64 + TPB - 1) / TPB, TPB, 0, stream>>>(rowptr, csr_src, as2, ad2, h2, b2, out, N);
}

// Round 6
// 160.505 us; speedup vs baseline: 2.7786x; 1.1274x over previous
//
#include <hip/hip_runtime.h>
#include <hip/hip_bf16.h>

#define TPB 256
#define NEG_SLOPE 0.2f
#define B1 256          // blocks for hist/place passes
#define DPB 512         // dsts per bucket
#define MAXNB 128       // max buckets (N <= 65536)

// ---------- helpers ----------
__device__ __forceinline__ int getIdx(const void* p, int is32, long long i) {
  return is32 ? ((const int*)p)[i] : (int)((const long long*)p)[i];
}

// Detect whether edge_index storage is int32 (flag=1) or int64 (flag=0).
__global__ void k_detect(const void* __restrict__ ei, long long n64, int* flag) {
  const unsigned long long* p = (const unsigned long long*)ei;
  int i = threadIdx.x;
  int is32 = (i < n64 && p[i] > 0xFFFFFFFFULL) ? 1 : 0;
  unsigned long long m = __ballot(is32);
  if (threadIdx.x == 0) *flag = (m != 0ULL) ? 1 : 0;
}

// ---------- CSR stage 1: per-block bucket histograms, transposed layout ----------
__global__ __launch_bounds__(TPB) void k_histA(
    const void* __restrict__ ei, const int* __restrict__ dflag, int E, int Etot,
    int* __restrict__ histA, int NB, int CH) {
  __shared__ int lh[MAXNB];
  int b = blockIdx.x, tid = threadIdx.x;
  for (int i = tid; i < NB; i += TPB) lh[i] = 0;
  __syncthreads();
  int f = *dflag;
  int beg = b * CH, end = min(beg + CH, Etot);
  for (int e = beg + tid; e < end; e += TPB) {
    int d = (e < E) ? getIdx(ei, f, (long long)E + e) : e - E;
    atomicAdd(&lh[d / DPB], 1);
  }
  __syncthreads();
  for (int i = tid; i < NB; i += TPB) histA[b * NB + i] = lh[i];  // [block][bucket]
}

// ---------- CSR stage 2: prefix bases (single block) ----------
__global__ __launch_bounds__(TPB) void k_scanA(
    const int* __restrict__ histA, int* __restrict__ blockBase,
    int* __restrict__ bucketBase, int NB) {
  __shared__ int sh[TPB];
  int t = threadIdx.x;
  int tot = 0;
  if (t < NB) {
    int run = 0;
    for (int b = 0; b < B1; ++b) {           // coalesced: histA[b*NB + t]
      int v = histA[b * NB + t];
      blockBase[b * NB + t] = run;           // intra-bucket prefix over blocks
      run += v;
    }
    tot = run;
  }
  sh[t] = tot;
  __syncthreads();
  for (int off = 1; off < TPB; off <<= 1) {
    int v = (t >= off) ? sh[t - off] : 0;
    __syncthreads();
    sh[t] += v;
    __syncthreads();
  }
  if (t < NB) bucketBase[t] = sh[t] - tot;   // exclusive
  if (t == TPB - 1) bucketBase[NB] = sh[TPB - 1];  // == Etot
}

// ---------- CSR stage 3: place (src,dst) pairs grouped by bucket ----------
__global__ __launch_bounds__(TPB) void k_placeB(
    const void* __restrict__ ei, const int* __restrict__ dflag, int E, int Etot,
    const int* __restrict__ blockBase, const int* __restrict__ bucketBase,
    int2* __restrict__ pairs, int NB, int CH) {
  __shared__ int cur[MAXNB];
  int b = blockIdx.x, tid = threadIdx.x;
  for (int i = tid; i < NB; i += TPB) cur[i] = blockBase[b * NB + i] + bucketBase[i];
  __syncthreads();
  int f = *dflag;
  int beg = b * CH, end = min(beg + CH, Etot);
  for (int e = beg + tid; e < end; e += TPB) {
    int s, d;
    if (e < E) {
      s = getIdx(ei, f, e);
      d = getIdx(ei, f, (long long)E + e);
    } else {
      s = d = e - E;
    }
    int pos = atomicAdd(&cur[d / DPB], 1);
    pairs[pos] = make_int2(s, d);
  }
}

// ---------- CSR stage 4: per-bucket hist+scan -> rowptr, then place csr_src ----------
__global__ __launch_bounds__(DPB) void k_bucket(
    const int2* __restrict__ pairs, const int* __restrict__ bucketBase,
    int* __restrict__ rowptr, int* __restrict__ csr_src, int N, int Etot) {
  __shared__ int cnt[DPB];
  __shared__ int sc[DPB];
  int g = blockIdx.x, tid = threadIdx.x;
  int base = g * DPB;
  int nd = N - base; if (nd > DPB) nd = DPB;
  cnt[tid] = 0;
  __syncthreads();
  int beg = bucketBase[g], end = bucketBase[g + 1];
  for (int j = beg + tid; j < end; j += DPB) atomicAdd(&cnt[pairs[j].y & (DPB - 1)], 1);
  __syncthreads();
  sc[tid] = cnt[tid];
  __syncthreads();
  for (int off = 1; off < DPB; off <<= 1) {
    int v = (tid >= off) ? sc[tid - off] : 0;
    __syncthreads();
    sc[tid] += v;
    __syncthreads();
  }
  int excl = beg + sc[tid] - cnt[tid];
  if (tid < nd) rowptr[base + tid] = excl;
  if (g == 0 && tid == 0) rowptr[N] = Etot;
  __syncthreads();
  cnt[tid] = excl;  // becomes cursor
  __syncthreads();
  for (int j = beg + tid; j < end; j += DPB) {
    int2 p = pairs[j];
    int pos = atomicAdd(&cnt[p.y & (DPB - 1)], 1);
    csr_src[pos] = p.x;
  }
}

// ---------- layer 1: h1 = x @ W1  (N x 64) @ (64 x 64), fused alpha dots ----------
__global__ __launch_bounds__(TPB) void k_gemm1(
    const float* __restrict__ x, const float* __restrict__ W1,
    const float* __restrict__ aS, const float* __restrict__ aD,
    float* __restrict__ h1, float* __restrict__ asrc, float* __restrict__ adst, int N) {
  __shared__ float Wl[64 * 64];
  __shared__ float xr[4][64];
  int t = threadIdx.x;
  for (int i = t; i < 64 * 64; i += TPB) Wl[i] = W1[i];
  int w = t >> 6, lane = t & 63;
  int node = blockIdx.x * 4 + w;
  if (node < N) xr[w][lane] = x[(size_t)node * 64 + lane];
  __syncthreads();
  if (node >= N) return;
  float acc = 0.f;
#pragma unroll
  for (int k = 0; k < 64; ++k) acc = fmaf(xr[w][k], Wl[k * 64 + lane], acc);
  h1[(size_t)node * 64 + lane] = acc;
  float vs = acc * aS[lane];
  float vd = acc * aD[lane];
#pragma unroll
  for (int m = 16; m >= 1; m >>= 1) {
    vs += __shfl_xor(vs, m, 64);
    vd += __shfl_xor(vd, m, 64);
  }
  if ((lane & 31) == 0) {
    asrc[node * 2 + (lane >> 5)] = vs;
    adst[node * 2 + (lane >> 5)] = vd;
  }
}

// ---------- fused layer-1 gather + layer-2 linear ----------
// Wave per node: gather/softmax-aggregate layer 1 (quarter-wave per edge,
// float4 rows), stage the finished out1 row in LDS (wave-private, lockstep
// ordering -> no barrier), then h2 = row @ W2 + alpha2 dots, all in-wave.
__global__ __launch_bounds__(TPB) void k_gather1f(
    const int* __restrict__ rowptr, const int* __restrict__ csr_src,
    const float* __restrict__ as1, const float* __restrict__ ad1,
    const float* __restrict__ h1, const float* __restrict__ b1,
    const float* __restrict__ W2, const float* __restrict__ aS2,
    const float* __restrict__ aD2,
    float* __restrict__ h2, float* __restrict__ as2, float* __restrict__ ad2, int N) {
  __shared__ float W2s[64 * 32];
  __shared__ float aS2s[32], aD2s[32];
  __shared__ float rowBuf[4][64];
  int t = threadIdx.x;
  for (int i = t; i < 64 * 32; i += TPB) W2s[i] = W2[i];
  if (t < 32) { aS2s[t] = aS2[t]; aD2s[t] = aD2[t]; }
  __syncthreads();

  int w = t >> 6, lane = t & 63;
  int node = blockIdx.x * 4 + w;
  if (node >= N) return;

  int q = lane >> 4, ql = lane & 15;
  int h = ql >> 3;  // head owning features [ql*4, ql*4+4)
  float ad = ad1[node * 2 + h];
  int beg = rowptr[node], end = rowptr[node + 1];
  float ax = 0.f, ay = 0.f, az = 0.f, aw = 0.f, den = 0.f;
  for (int j = beg + q; j < end; j += 4) {
    int s = csr_src[j];
    float v = as1[s * 2 + h] + ad;
    float4 g = *(const float4*)(h1 + (size_t)s * 64 + ql * 4);
    v = v > 0.f ? v : NEG_SLOPE * v;
    float wgt = __expf(v);
    ax = fmaf(wgt, g.x, ax);
    ay = fmaf(wgt, g.y, ay);
    az = fmaf(wgt, g.z, az);
    aw = fmaf(wgt, g.w, aw);
    den += wgt;
  }
#pragma unroll
  for (int m = 16; m <= 32; m <<= 1) {
    ax += __shfl_xor(ax, m, 64);
    ay += __shfl_xor(ay, m, 64);
    az += __shfl_xor(az, m, 64);
    aw += __shfl_xor(aw, m, 64);
    den += __shfl_xor(den, m, 64);
  }
  if (q == 0) {
    float inv = 1.f / (den + 1e-16f);
    float4 bb = *(const float4*)(b1 + ql * 4);
    float4 o;
    o.x = fmaf(ax, inv, bb.x);
    o.y = fmaf(ay, inv, bb.y);
    o.z = fmaf(az, inv, bb.z);
    o.w = fmaf(aw, inv, bb.w);
    o.x = o.x > 0.f ? o.x : 0.f;
    o.y = o.y > 0.f ? o.y : 0.f;
    o.z = o.z > 0.f ? o.z : 0.f;
    o.w = o.w > 0.f ? o.w : 0.f;
    *(float4*)&rowBuf[w][ql * 4] = o;
  }
  // wave-internal LDS handoff: same wave, in-order LDS pipe -> visible
  int c = lane & 31, half = lane >> 5;
  float acc2 = 0.f;
#pragma unroll
  for (int k = 0; k < 32; ++k)
    acc2 = fmaf(rowBuf[w][half * 32 + k], W2s[(half * 32 + k) * 32 + c], acc2);
  acc2 += __shfl_xor(acc2, 32, 64);  // full dot in all lanes
  if (half == 0) h2[(size_t)node * 32 + c] = acc2;
  float vs = acc2 * aS2s[c];
  float vd = acc2 * aD2s[c];
#pragma unroll
  for (int m = 16; m >= 1; m >>= 1) {
    vs += __shfl_xor(vs, m, 64);
    vd += __shfl_xor(vd, m, 64);
  }
  if (lane == 0) {
    as2[node] = vs;
    ad2[node] = vd;
  }
}

// ---------- layer 2 gather: wave/node, 8-lane-group/edge, inline softmax weight ----------
__global__ __launch_bounds__(TPB) void k_gather2(
    const int* __restrict__ rowptr, const int* __restrict__ csr_src,
    const float* __restrict__ as2, const float* __restrict__ ad2,
    const float* __restrict__ h2, const float* __restrict__ b,
    float* __restrict__ out, int N) {
  int wid = (int)((blockIdx.x * (unsigned)TPB + threadIdx.x) >> 6);
  int lane = threadIdx.x & 63;
  if (wid >= N) return;
  int g = lane >> 3, gl = lane & 7;
  float ad = ad2[wid];
  int beg = rowptr[wid], end = rowptr[wid + 1];
  float ax = 0.f, ay = 0.f, az = 0.f, aw = 0.f, den = 0.f;
  for (int j = beg + g; j < end; j += 8) {
    int s = csr_src[j];
    float v = as2[s] + ad;
    float4 v4 = *(const float4*)(h2 + (size_t)s * 32 + gl * 4);
    v = v > 0.f ? v : NEG_SLOPE * v;
    float w = __expf(v);
    ax = fmaf(w, v4.x, ax);
    ay = fmaf(w, v4.y, ay);
    az = fmaf(w, v4.z, az);
    aw = fmaf(w, v4.w, aw);
    den += w;
  }
#pragma unroll
  for (int m = 8; m <= 32; m <<= 1) {
    ax += __shfl_xor(ax, m, 64);
    ay += __shfl_xor(ay, m, 64);
    az += __shfl_xor(az, m, 64);
    aw += __shfl_xor(aw, m, 64);
    den += __shfl_xor(den, m, 64);
  }
  if (g == 0) {
    float inv = 1.f / (den + 1e-16f);
    float4 bb = *(const float4*)(b + gl * 4);
    float4 o;
    o.x = fmaf(ax, inv, bb.x);
    o.y = fmaf(ay, inv, bb.y);
    o.z = fmaf(az, inv, bb.z);
    o.w = fmaf(aw, inv, bb.w);
    *(float4*)(out + (size_t)wid * 32 + gl * 4) = o;
  }
}

extern "C" void kernel_launch(void* const* d_in, const int* in_sizes, int n_in,
                              void* d_out, int out_size, void* d_ws, size_t ws_size,
                              hipStream_t stream) {
  const float* x   = (const float*)d_in[0];
  const void*  ei  = d_in[1];
  const float* W1  = (const float*)d_in[2];
  const float* aS1 = (const float*)d_in[3];
  const float* aD1 = (const float*)d_in[4];
  const float* b1  = (const float*)d_in[5];
  const float* W2  = (const float*)d_in[6];
  const float* aS2 = (const float*)d_in[7];
  const float* aD2 = (const float*)d_in[8];
  const float* b2  = (const float*)d_in[9];
  float* out = (float*)d_out;

  int N = in_sizes[0] / 64;
  int E = in_sizes[1] / 2;
  int Etot = E + N;
  int NB = (N + DPB - 1) / DPB;         // dst buckets
  int CH = (Etot + B1 - 1) / B1;        // edges per hist/place block

  float* W = (float*)d_ws;
  size_t o = 0;
  float* h1 = W + o; o += (size_t)N * 64;
  // pairs (int2, Etot) shares storage with h2 (N*32 floats): disjoint lifetimes
  size_t regB = (size_t)(2 * (size_t)Etot > (size_t)N * 32 ? 2 * (size_t)Etot : (size_t)N * 32);
  int2* pairs = (int2*)(W + o);
  float* h2   = W + o;
  o += regB;
  float* as1  = W + o; o += (size_t)N * 2;
  float* ad1  = W + o; o += (size_t)N * 2;
  float* as2  = W + o; o += (size_t)N;
  float* ad2  = W + o; o += (size_t)N;
  int* ip = (int*)(W + o);
  size_t io = 0;
  int* histA      = ip + io; io += (size_t)NB * B1;
  int* blockBase  = ip + io; io += (size_t)NB * B1;
  int* bucketBase = ip + io; io += NB + 1;
  int* rowptr     = ip + io; io += N + 1;
  int* csr_src    = ip + io; io += Etot;
  int* flag       = ip + io; io += 1;

  k_detect<<<1, 64, 0, stream>>>(ei, (long long)E, flag);

  // CSR build: LDS-binned counting sort, 512-dst buckets, no global return-atomics
  k_histA<<<B1, TPB, 0, stream>>>(ei, flag, E, Etot, histA, NB, CH);
  k_scanA<<<1, TPB, 0, stream>>>(histA, blockBase, bucketBase, NB);
  k_placeB<<<B1, TPB, 0, stream>>>(ei, flag, E, Etot, blockBase, bucketBase, pairs, NB, CH);
  k_bucket<<<NB, DPB, 0, stream>>>(pairs, bucketBase, rowptr, csr_src, N, Etot);

  // layer 1 + fused layer-2 linear
  k_gemm1<<<(N + 3) / 4, TPB, 0, stream>>>(x, W1, aS1, aD1, h1, as1, ad1, N);
  k_gather1f<<<(N + 3) / 4, TPB, 0, stream>>>(rowptr, csr_src, as1, ad1, h1, b1,
                                              W2, aS2, aD2, h2, as2, ad2, N);

  // layer 2 gather -> output
  k_gather2<<<(N * 64 + TPB - 1) / TPB, TPB, 0, stream>>>(rowptr, csr_src, as2, ad2, h2, b2, out, N);
}

// Round 7
// 150.161 us; speedup vs baseline: 2.9700x; 1.0689x over previous
//
#include <hip/hip_runtime.h>
#include <hip/hip_fp16.h>

#define TPB 256
#define NEG_SLOPE 0.2f
#define B1 256          // blocks for hist/place passes
#define DPB 512         // dsts per bucket
#define MAXNB 128       // max buckets (N <= 65536)

// ---------- helpers ----------
__device__ __forceinline__ int getIdx(const void* p, int is32, long long i) {
  return is32 ? ((const int*)p)[i] : (int)((const long long*)p)[i];
}

// unpack 8 fp16 (loaded as float4) to 8 fp32
__device__ __forceinline__ void unpack8(const float4& r, float* f) {
  const __half2* hp = (const __half2*)&r;
#pragma unroll
  for (int i = 0; i < 4; ++i) {
    float2 t = __half22float2(hp[i]);
    f[2 * i] = t.x;
    f[2 * i + 1] = t.y;
  }
}

// ---------- CSR stage 1: per-block bucket histograms (inline dtype sniff) ----------
__global__ __launch_bounds__(TPB) void k_histA(
    const void* __restrict__ ei, int E, int Etot,
    int* __restrict__ histA, int NB, int CH) {
  __shared__ int lh[MAXNB];
  __shared__ int sflag;
  int b = blockIdx.x, tid = threadIdx.x;
  for (int i = tid; i < NB; i += TPB) lh[i] = 0;
  if (tid < 64) {  // wave 0: sniff int32 vs int64 storage (ids < 2^31)
    const unsigned long long* p = (const unsigned long long*)ei;
    unsigned long long m = __ballot(p[tid] > 0xFFFFFFFFULL);
    if (tid == 0) sflag = (m != 0ULL) ? 1 : 0;
  }
  __syncthreads();
  int f = sflag;
  int beg = b * CH, end = min(beg + CH, Etot);
  for (int e = beg + tid; e < end; e += TPB) {
    int d = (e < E) ? getIdx(ei, f, (long long)E + e) : e - E;
    atomicAdd(&lh[d / DPB], 1);
  }
  __syncthreads();
  for (int i = tid; i < NB; i += TPB) histA[b * NB + i] = lh[i];  // [block][bucket]
}

// ---------- CSR stage 2: prefix bases (single block) ----------
__global__ __launch_bounds__(TPB) void k_scanA(
    const int* __restrict__ histA, int* __restrict__ blockBase,
    int* __restrict__ bucketBase, int NB) {
  __shared__ int sh[TPB];
  int t = threadIdx.x;
  int tot = 0;
  if (t < NB) {
    int run = 0;
    for (int b = 0; b < B1; ++b) {           // coalesced: histA[b*NB + t]
      int v = histA[b * NB + t];
      blockBase[b * NB + t] = run;           // intra-bucket prefix over blocks
      run += v;
    }
    tot = run;
  }
  sh[t] = tot;
  __syncthreads();
  for (int off = 1; off < TPB; off <<= 1) {
    int v = (t >= off) ? sh[t - off] : 0;
    __syncthreads();
    sh[t] += v;
    __syncthreads();
  }
  if (t < NB) bucketBase[t] = sh[t] - tot;   // exclusive
  if (t == TPB - 1) bucketBase[NB] = sh[TPB - 1];  // == Etot
}

// ---------- CSR stage 3: place (src,dst) pairs grouped by bucket ----------
__global__ __launch_bounds__(TPB) void k_placeB(
    const void* __restrict__ ei, int E, int Etot,
    const int* __restrict__ blockBase, const int* __restrict__ bucketBase,
    int2* __restrict__ pairs, int NB, int CH) {
  __shared__ int cur[MAXNB];
  __shared__ int sflag;
  int b = blockIdx.x, tid = threadIdx.x;
  for (int i = tid; i < NB; i += TPB) cur[i] = blockBase[b * NB + i] + bucketBase[i];
  if (tid < 64) {
    const unsigned long long* p = (const unsigned long long*)ei;
    unsigned long long m = __ballot(p[tid] > 0xFFFFFFFFULL);
    if (tid == 0) sflag = (m != 0ULL) ? 1 : 0;
  }
  __syncthreads();
  int f = sflag;
  int beg = b * CH, end = min(beg + CH, Etot);
  for (int e = beg + tid; e < end; e += TPB) {
    int s, d;
    if (e < E) {
      s = getIdx(ei, f, e);
      d = getIdx(ei, f, (long long)E + e);
    } else {
      s = d = e - E;
    }
    int pos = atomicAdd(&cur[d / DPB], 1);
    pairs[pos] = make_int2(s, d);
  }
}

// ---------- CSR stage 4: per-bucket hist+scan -> rowptr, then place csr_src ----------
__global__ __launch_bounds__(DPB) void k_bucket(
    const int2* __restrict__ pairs, const int* __restrict__ bucketBase,
    int* __restrict__ rowptr, int* __restrict__ csr_src, int N, int Etot) {
  __shared__ int cnt[DPB];
  __shared__ int sc[DPB];
  int g = blockIdx.x, tid = threadIdx.x;
  int base = g * DPB;
  int nd = N - base; if (nd > DPB) nd = DPB;
  cnt[tid] = 0;
  __syncthreads();
  int beg = bucketBase[g], end = bucketBase[g + 1];
  for (int j = beg + tid; j < end; j += DPB) atomicAdd(&cnt[pairs[j].y & (DPB - 1)], 1);
  __syncthreads();
  sc[tid] = cnt[tid];
  __syncthreads();
  for (int off = 1; off < DPB; off <<= 1) {
    int v = (tid >= off) ? sc[tid - off] : 0;
    __syncthreads();
    sc[tid] += v;
    __syncthreads();
  }
  int excl = beg + sc[tid] - cnt[tid];
  if (tid < nd) rowptr[base + tid] = excl;
  if (g == 0 && tid == 0) rowptr[N] = Etot;
  __syncthreads();
  cnt[tid] = excl;  // becomes cursor
  __syncthreads();
  for (int j = beg + tid; j < end; j += DPB) {
    int2 p = pairs[j];
    int pos = atomicAdd(&cnt[p.y & (DPB - 1)], 1);
    csr_src[pos] = p.x;
  }
}

// ---------- layer 1: h1 = x @ W1 (fp16 out), fused alpha dots ----------
__global__ __launch_bounds__(TPB) void k_gemm1(
    const float* __restrict__ x, const float* __restrict__ W1,
    const float* __restrict__ aS, const float* __restrict__ aD,
    __half* __restrict__ h1, float* __restrict__ asrc, float* __restrict__ adst, int N) {
  __shared__ float Wl[64 * 64];
  __shared__ float xr[4][64];
  int t = threadIdx.x;
  for (int i = t; i < 64 * 64; i += TPB) Wl[i] = W1[i];
  int w = t >> 6, lane = t & 63;
  int node = blockIdx.x * 4 + w;
  if (node < N) xr[w][lane] = x[(size_t)node * 64 + lane];
  __syncthreads();
  if (node >= N) return;
  float acc = 0.f;
#pragma unroll
  for (int k = 0; k < 64; ++k) acc = fmaf(xr[w][k], Wl[k * 64 + lane], acc);
  h1[(size_t)node * 64 + lane] = __float2half(acc);
  float vs = acc * aS[lane];
  float vd = acc * aD[lane];
#pragma unroll
  for (int m = 16; m >= 1; m >>= 1) {
    vs += __shfl_xor(vs, m, 64);
    vd += __shfl_xor(vd, m, 64);
  }
  if ((lane & 31) == 0) {
    asrc[node * 2 + (lane >> 5)] = vs;
    adst[node * 2 + (lane >> 5)] = vd;
  }
}

// ---------- fused layer-1 gather + layer-2 linear ----------
// Wave per node; 8-lane group per edge (16B fp16 loads, 8 edges in flight);
// out1 row staged in wave-private LDS; then h2 = row @ W2 + alpha2 dots.
__global__ __launch_bounds__(TPB) void k_gather1f(
    const int* __restrict__ rowptr, const int* __restrict__ csr_src,
    const float* __restrict__ as1, const float* __restrict__ ad1,
    const __half* __restrict__ h1, const float* __restrict__ b1,
    const float* __restrict__ W2, const float* __restrict__ aS2,
    const float* __restrict__ aD2,
    __half* __restrict__ h2, float* __restrict__ as2, float* __restrict__ ad2, int N) {
  __shared__ float W2s[64 * 32];
  __shared__ float aS2s[32], aD2s[32];
  __shared__ float rowBuf[4][64];
  int t = threadIdx.x;
  for (int i = t; i < 64 * 32; i += TPB) W2s[i] = W2[i];
  if (t < 32) { aS2s[t] = aS2[t]; aD2s[t] = aD2[t]; }
  __syncthreads();

  int w = t >> 6, lane = t & 63;
  int node = blockIdx.x * 4 + w;
  if (node >= N) return;

  int g8 = lane >> 3, l8 = lane & 7;   // 8 groups of 8 lanes
  int h = l8 >> 2;                     // head for features [l8*8, l8*8+8)
  float ad = ad1[node * 2 + h];
  int beg = rowptr[node], end = rowptr[node + 1];
  float a[8] = {0.f, 0.f, 0.f, 0.f, 0.f, 0.f, 0.f, 0.f};
  float den = 0.f;
  for (int j = beg + g8; j < end; j += 8) {
    int s = csr_src[j];
    float v = as1[s * 2 + h] + ad;
    float4 r = *(const float4*)(h1 + (size_t)s * 64 + l8 * 8);
    v = v > 0.f ? v : NEG_SLOPE * v;
    float wgt = __expf(v);
    float f[8];
    unpack8(r, f);
#pragma unroll
    for (int i = 0; i < 8; ++i) a[i] = fmaf(wgt, f[i], a[i]);
    den += wgt;
  }
#pragma unroll
  for (int m = 8; m <= 32; m <<= 1) {
#pragma unroll
    for (int i = 0; i < 8; ++i) a[i] += __shfl_xor(a[i], m, 64);
    den += __shfl_xor(den, m, 64);
  }
  if (g8 == 0) {  // lanes 0..7 own features [lane*8, lane*8+8)
    float inv = 1.f / (den + 1e-16f);
#pragma unroll
    for (int i = 0; i < 8; ++i) {
      float o = fmaf(a[i], inv, b1[l8 * 8 + i]);
      rowBuf[w][l8 * 8 + i] = o > 0.f ? o : 0.f;
    }
  }
  // wave-internal LDS handoff: same wave, in-order LDS pipe -> visible
  int c = lane & 31, half = lane >> 5;
  float acc2 = 0.f;
#pragma unroll
  for (int k = 0; k < 32; ++k)
    acc2 = fmaf(rowBuf[w][half * 32 + k], W2s[(half * 32 + k) * 32 + c], acc2);
  acc2 += __shfl_xor(acc2, 32, 64);  // full dot in all lanes
  if (half == 0) h2[(size_t)node * 32 + c] = __float2half(acc2);
  float vs = acc2 * aS2s[c];
  float vd = acc2 * aD2s[c];
#pragma unroll
  for (int m = 16; m >= 1; m >>= 1) {
    vs += __shfl_xor(vs, m, 64);
    vd += __shfl_xor(vd, m, 64);
  }
  if (lane == 0) {
    as2[node] = vs;
    ad2[node] = vd;
  }
}

// ---------- layer 2 gather: wave/node, 4-lane group/edge (16 edges in flight) ----------
__global__ __launch_bounds__(TPB) void k_gather2(
    const int* __restrict__ rowptr, const int* __restrict__ csr_src,
    const float* __restrict__ as2, const float* __restrict__ ad2,
    const __half* __restrict__ h2, const float* __restrict__ b,
    float* __restrict__ out, int N) {
  int wid = (int)((blockIdx.x * (unsigned)TPB + threadIdx.x) >> 6);
  int lane = threadIdx.x & 63;
  if (wid >= N) return;
  int g4 = lane >> 2, l4 = lane & 3;   // 16 groups of 4 lanes
  float ad = ad2[wid];
  int beg = rowptr[wid], end = rowptr[wid + 1];
  float a[8] = {0.f, 0.f, 0.f, 0.f, 0.f, 0.f, 0.f, 0.f};
  float den = 0.f;
  for (int j = beg + g4; j < end; j += 16) {
    int s = csr_src[j];
    float v = as2[s] + ad;
    float4 r = *(const float4*)(h2 + (size_t)s * 32 + l4 * 8);
    v = v > 0.f ? v : NEG_SLOPE * v;
    float wgt = __expf(v);
    float f[8];
    unpack8(r, f);
#pragma unroll
    for (int i = 0; i < 8; ++i) a[i] = fmaf(wgt, f[i], a[i]);
    den += wgt;
  }
#pragma unroll
  for (int m = 4; m <= 32; m <<= 1) {
#pragma unroll
    for (int i = 0; i < 8; ++i) a[i] += __shfl_xor(a[i], m, 64);
    den += __shfl_xor(den, m, 64);
  }
  if (g4 == 0) {  // lanes 0..3 own features [lane*8, lane*8+8)
    float inv = 1.f / (den + 1e-16f);
    float o[8];
#pragma unroll
    for (int i = 0; i < 8; ++i) o[i] = fmaf(a[i], inv, b[l4 * 8 + i]);
    float4* dst = (float4*)(out + (size_t)wid * 32 + l4 * 8);
    dst[0] = make_float4(o[0], o[1], o[2], o[3]);
    dst[1] = make_float4(o[4], o[5], o[6], o[7]);
  }
}

extern "C" void kernel_launch(void* const* d_in, const int* in_sizes, int n_in,
                              void* d_out, int out_size, void* d_ws, size_t ws_size,
                              hipStream_t stream) {
  const float* x   = (const float*)d_in[0];
  const void*  ei  = d_in[1];
  const float* W1  = (const float*)d_in[2];
  const float* aS1 = (const float*)d_in[3];
  const float* aD1 = (const float*)d_in[4];
  const float* b1  = (const float*)d_in[5];
  const float* W2  = (const float*)d_in[6];
  const float* aS2 = (const float*)d_in[7];
  const float* aD2 = (const float*)d_in[8];
  const float* b2  = (const float*)d_in[9];
  float* out = (float*)d_out;

  int N = in_sizes[0] / 64;
  int E = in_sizes[1] / 2;
  int Etot = E + N;
  int NB = (N + DPB - 1) / DPB;         // dst buckets
  int CH = (Etot + B1 - 1) / B1;        // edges per hist/place block

  float* W = (float*)d_ws;
  size_t o = 0;
  __half* h1 = (__half*)(W + o); o += (size_t)N * 32;   // N*64 halfs
  // pairs (int2, Etot) shares storage with h2 (N*32 halfs): disjoint lifetimes
  size_t regB = (size_t)(2 * (size_t)Etot > (size_t)N * 16 ? 2 * (size_t)Etot : (size_t)N * 16);
  int2* pairs = (int2*)(W + o);
  __half* h2  = (__half*)(W + o);
  o += regB;
  float* as1  = W + o; o += (size_t)N * 2;
  float* ad1  = W + o; o += (size_t)N * 2;
  float* as2  = W + o; o += (size_t)N;
  float* ad2  = W + o; o += (size_t)N;
  int* ip = (int*)(W + o);
  size_t io = 0;
  int* histA      = ip + io; io += (size_t)NB * B1;
  int* blockBase  = ip + io; io += (size_t)NB * B1;
  int* bucketBase = ip + io; io += NB + 1;
  int* rowptr     = ip + io; io += N + 1;
  int* csr_src    = ip + io; io += Etot;

  // CSR build: LDS-binned counting sort, 512-dst buckets, no global return-atomics
  k_histA<<<B1, TPB, 0, stream>>>(ei, E, Etot, histA, NB, CH);
  k_scanA<<<1, TPB, 0, stream>>>(histA, blockBase, bucketBase, NB);
  k_placeB<<<B1, TPB, 0, stream>>>(ei, E, Etot, blockBase, bucketBase, pairs, NB, CH);
  k_bucket<<<NB, DPB, 0, stream>>>(pairs, bucketBase, rowptr, csr_src, N, Etot);

  // layer 1 + fused layer-2 linear
  k_gemm1<<<(N + 3) / 4, TPB, 0, stream>>>(x, W1, aS1, aD1, h1, as1, ad1, N);
  k_gather1f<<<(N + 3) / 4, TPB, 0, stream>>>(rowptr, csr_src, as1, ad1, h1, b1,
                                              W2, aS2, aD2, h2, as2, ad2, N);

  // layer 2 gather -> output
  k_gather2<<<(N * 64 + TPB - 1) / TPB, TPB, 0, stream>>>(rowptr, csr_src, as2, ad2, h2, b2, out, N);
}